// Round 13
// baseline (211.139 us; speedup 1.0000x reference)
//
#include <hip/hip_runtime.h>
#include <math.h>

#define H 32
#define BSEG 16
#define CHUNKS 32

#define FMA4(acc, s, wv) { acc[0]=fmaf(s,wv.x,acc[0]); acc[1]=fmaf(s,wv.y,acc[1]); acc[2]=fmaf(s,wv.z,acc[2]); acc[3]=fmaf(s,wv.w,acc[3]); }

__device__ __forceinline__ float sigmoidf_(float x){ return 1.f/(1.f+expf(-x)); }

__device__ __forceinline__ unsigned int fenc(float f) {
    int i = __float_as_int(f);
    return (i >= 0) ? ((unsigned int)i | 0x80000000u) : ~(unsigned int)i;
}
__device__ __forceinline__ float fdec(unsigned int u) {
    int i = (u & 0x80000000u) ? (int)(u & 0x7FFFFFFFu) : (int)(~u);
    return __int_as_float(i);
}

// ---------------- prep: transposed GRU weights, fused biases, qvec, masked edge matrices, zero cnt ----------------
__global__ __launch_bounds__(512) void k_prep(
    const float* __restrict__ gru_wi, const float* __restrict__ gru_wh,
    const float* __restrict__ gru_bi, const float* __restrict__ gru_bh,
    const float* __restrict__ lstm_bi, const float* __restrict__ lstm_bh,
    const float* __restrict__ e1w, const float* __restrict__ e1b, const float* __restrict__ e2w,
    float* __restrict__ WI, float* __restrict__ WH, float* __restrict__ BS,
    float* __restrict__ MP, float* __restrict__ MM, int* __restrict__ flag,
    float* __restrict__ qvec, unsigned int* __restrict__ segmax,
    float* __restrict__ ssum, float* __restrict__ vsum,
    int* __restrict__ cnt, int N)
{
    int t = threadIdx.x;
    for (int i = t; i < N; i += 512) cnt[i] = 0;
    for (int idx = t; idx < 3072; idx += 512) {
        int k = idx >> 10, rem = idx & 1023, i = rem >> 5, o = rem & 31;
        WI[idx] = gru_wi[(k*32 + o)*32 + i];
        WH[idx] = gru_wh[(k*32 + o)*32 + i];
    }
    for (int idx = t; idx < 1024; idx += 512) {
        float mp = 0.f, mm = 0.f;
        #pragma unroll
        for (int k = 0; k < 8; ++k) {
            float w = e1w[k];
            float v = e2w[k*1024 + idx];
            if (w > 0.f) mp = fmaf(w, v, mp);
            if (w < 0.f) mm = fmaf(w, v, mm);
        }
        MP[idx] = mp;
        MM[idx] = mm;
    }
    if (t == 0) {
        int z = 1;
        for (int k = 0; k < 8; ++k) if (e1b[k] != 0.f) z = 0;
        flag[0] = z;
    }
    if (t < 32) {
        BS[t]      = gru_bi[t]      + gru_bh[t];
        BS[32 + t] = gru_bi[32 + t] + gru_bh[32 + t];
        BS[64 + t] = gru_bi[64 + t];
        BS[96 + t] = gru_bh[64 + t];
    }
    if (t < H) {
        float g0 = lstm_bi[t] + lstm_bh[t];
        float g2 = lstm_bi[2*H + t] + lstm_bh[2*H + t];
        float g3 = lstm_bi[3*H + t] + lstm_bh[3*H + t];
        float ig = sigmoidf_(g0);
        float gg = tanhf(g2);
        float og = sigmoidf_(g3);
        qvec[t] = og * tanhf(ig * gg);
    }
    for (int i = t; i < BSEG; i += 512) { segmax[i] = 0u; ssum[i] = 0.f; }
    for (int i = t; i < BSEG*H; i += 512) vsum[i] = 0.f;
}

// ---------------- CSR build: count -> scan -> scatter ----------------
__global__ __launch_bounds__(256) void k_count(const int* __restrict__ ei, int* __restrict__ cnt, int E)
{
    int e = blockIdx.x * 256 + threadIdx.x;
    if (e < E) atomicAdd(&cnt[ei[E + e]], 1);
}

__global__ __launch_bounds__(1024) void k_scan(
    const int* __restrict__ cnt, int* __restrict__ rowptr, int* __restrict__ cursor, int N)
{
    __shared__ int part[1024];
    int t = threadIdx.x;
    int chunk = (N + 1023) >> 10;
    int base = t * chunk;
    int s = 0;
    for (int i = 0; i < chunk; ++i) {
        int idx = base + i;
        if (idx < N) s += cnt[idx];
    }
    part[t] = s;
    __syncthreads();
    for (int off = 1; off < 1024; off <<= 1) {
        int add = (t >= off) ? part[t - off] : 0;
        __syncthreads();
        part[t] += add;
        __syncthreads();
    }
    int run = part[t] - s;                 // exclusive prefix for this chunk
    for (int i = 0; i < chunk; ++i) {
        int idx = base + i;
        if (idx < N) {
            rowptr[idx] = run;
            cursor[idx] = run;
            run += cnt[idx];
        }
    }
    if (t == 1023) rowptr[N] = part[1023];
}

__global__ __launch_bounds__(256) void k_scatter(
    const int* __restrict__ ei, const float* __restrict__ ea, int* __restrict__ cursor,
    int* __restrict__ esrc, float* __restrict__ eattr, int E)
{
    int e = blockIdx.x * 256 + threadIdx.x;
    if (e >= E) return;
    int dst = ei[E + e];
    int pos = atomicAdd(&cursor[dst], 1);
    esrc[pos] = ei[e];
    eattr[pos] = ea[e];
}

// ---- LDS-based K=32 passes, single node per lane (k_tab uses these) ----
__device__ __forceinline__ void pass1_lds(const float* sm, int xb, int w0, int fg4, float a[4])
{
    #pragma unroll 2
    for (int i4 = 0; i4 < 32; i4 += 4) {
        float4 xv  = *(const float4*)&sm[xb + i4];
        float4 w00 = *(const float4*)&sm[w0 + (i4+0)*32 + fg4];
        float4 w01 = *(const float4*)&sm[w0 + (i4+1)*32 + fg4];
        float4 w02 = *(const float4*)&sm[w0 + (i4+2)*32 + fg4];
        float4 w03 = *(const float4*)&sm[w0 + (i4+3)*32 + fg4];
        FMA4(a, xv.x, w00) FMA4(a, xv.y, w01) FMA4(a, xv.z, w02) FMA4(a, xv.w, w03)
    }
}

// ---- dual-node K=32 passes (k_gru): one weight read feeds both nodes ----
__device__ __forceinline__ void pass2_lds2(const float* sm, int xb0, int xb1,
                                           int w0, int w1, int fg4,
                                           float a0[4], float b0[4],
                                           float a1[4], float b1[4])
{
    #pragma unroll 2
    for (int i4 = 0; i4 < 32; i4 += 4) {
        float4 x0  = *(const float4*)&sm[xb0 + i4];
        float4 x1  = *(const float4*)&sm[xb1 + i4];
        float4 w00 = *(const float4*)&sm[w0 + (i4+0)*32 + fg4];
        float4 w01 = *(const float4*)&sm[w0 + (i4+1)*32 + fg4];
        float4 w02 = *(const float4*)&sm[w0 + (i4+2)*32 + fg4];
        float4 w03 = *(const float4*)&sm[w0 + (i4+3)*32 + fg4];
        float4 w10 = *(const float4*)&sm[w1 + (i4+0)*32 + fg4];
        float4 w11 = *(const float4*)&sm[w1 + (i4+1)*32 + fg4];
        float4 w12 = *(const float4*)&sm[w1 + (i4+2)*32 + fg4];
        float4 w13 = *(const float4*)&sm[w1 + (i4+3)*32 + fg4];
        FMA4(a0, x0.x, w00) FMA4(a0, x0.y, w01) FMA4(a0, x0.z, w02) FMA4(a0, x0.w, w03)
        FMA4(b0, x0.x, w10) FMA4(b0, x0.y, w11) FMA4(b0, x0.z, w12) FMA4(b0, x0.w, w13)
        FMA4(a1, x1.x, w00) FMA4(a1, x1.y, w01) FMA4(a1, x1.z, w02) FMA4(a1, x1.w, w03)
        FMA4(b1, x1.x, w10) FMA4(b1, x1.y, w11) FMA4(b1, x1.z, w12) FMA4(b1, x1.w, w13)
    }
}

__device__ __forceinline__ void pass1_lds2(const float* sm, int xb0, int xb1,
                                           int w0, int fg4, float a0[4], float a1[4])
{
    #pragma unroll 2
    for (int i4 = 0; i4 < 32; i4 += 4) {
        float4 x0  = *(const float4*)&sm[xb0 + i4];
        float4 x1  = *(const float4*)&sm[xb1 + i4];
        float4 w00 = *(const float4*)&sm[w0 + (i4+0)*32 + fg4];
        float4 w01 = *(const float4*)&sm[w0 + (i4+1)*32 + fg4];
        float4 w02 = *(const float4*)&sm[w0 + (i4+2)*32 + fg4];
        float4 w03 = *(const float4*)&sm[w0 + (i4+3)*32 + fg4];
        FMA4(a0, x0.x, w00) FMA4(a0, x0.y, w01) FMA4(a0, x0.z, w02) FMA4(a0, x0.w, w03)
        FMA4(a1, x1.x, w00) FMA4(a1, x1.y, w01) FMA4(a1, x1.z, w02) FMA4(a1, x1.w, w03)
    }
}

// ---------------- tab: proj fused + initial table. fast: T[n] stride 96; fallback: G[n] stride 288 ----------------
#define TW 3072
__global__ __launch_bounds__(256, 2) void k_tab(
    const float* __restrict__ x, const float* __restrict__ proj_w, const float* __restrict__ proj_b,
    const float* __restrict__ e2w, const float* __restrict__ e2b,
    const float* __restrict__ MP, const float* __restrict__ MM, const int* __restrict__ flag,
    float* __restrict__ h, float* __restrict__ A, int N)
{
    __shared__ float sm[TW + 4*288];
    int tid = threadIdx.x;
    int lane = tid & 63;
    int w = tid >> 6;
    int fg = lane & 7, fg4 = fg*4;
    int nw = lane >> 3;
    int n = (blockIdx.x * 4 + w) * 8 + nw;
    bool valid = (n < N);
    int nc = valid ? n : (N - 1);
    int xb = TW + w*288 + nw*36;

    // proj fused: h row for this node
    {
        float4 xv = *(const float4*)&x[nc*4];
        float r_[4];
        #pragma unroll
        for (int j = 0; j < 4; ++j) {
            int o = fg4 + j;
            float a = proj_b[o];
            a = fmaf(xv.x, proj_w[0*32 + o], a);
            a = fmaf(xv.y, proj_w[1*32 + o], a);
            a = fmaf(xv.z, proj_w[2*32 + o], a);
            a = fmaf(xv.w, proj_w[3*32 + o], a);
            r_[j] = fmaxf(a, 0.f);
        }
        if (valid) *(float4*)&h[n*32 + fg4] = make_float4(r_[0], r_[1], r_[2], r_[3]);
        *(float4*)&sm[xb + fg4] = make_float4(r_[0], r_[1], r_[2], r_[3]);
    }

    if (flag[0]) {
        float4* s4 = (float4*)sm;
        for (int i = tid; i < 768; i += 256) {
            const float4* src = (i < 256) ? (const float4*)MP
                              : (i < 512) ? (const float4*)MM
                                          : (const float4*)e2b;
            s4[i] = src[i & 255];
        }
        __syncthreads();
        #pragma unroll 1
        for (int cc = 0; cc < 3; ++cc) {
            float acc[4] = {0.f, 0.f, 0.f, 0.f};
            pass1_lds(sm, xb, cc*1024, fg4, acc);
            if (valid)
                *(float4*)&A[(size_t)n*96 + cc*32 + fg4] =
                    make_float4(acc[0], acc[1], acc[2], acc[3]);
        }
    } else {
        #pragma unroll 1
        for (int cg = 0; cg < 3; ++cg) {
            __syncthreads();
            float4* s4 = (float4*)sm;
            for (int i = tid; i < 768; i += 256) {
                int c = cg*3 + (i >> 8);
                const float4* src = (c < 8) ? (const float4*)(e2w + (size_t)c*1024)
                                            : (const float4*)e2b;
                s4[i] = src[i & 255];
            }
            __syncthreads();
            #pragma unroll 1
            for (int cc = 0; cc < 3; ++cc) {
                float acc[4] = {0.f, 0.f, 0.f, 0.f};
                pass1_lds(sm, xb, cc*1024, fg4, acc);
                if (valid)
                    *(float4*)&A[(size_t)n*288 + (cg*3+cc)*32 + fg4] =
                        make_float4(acc[0], acc[1], acc[2], acc[3]);
            }
        }
    }
}

// ---------------- fused iteration: 2 nodes/lane. CSR gather (dual chain) -> GRU -> h; next-table ----------------
// LDS floats: ROOT[0,1024) WH[1024,4096) WI[4096,7168) MW[7168,10240) X[10240, +4*576)
#define XGR 10240
__global__ __launch_bounds__(256, 2) void k_gru(
    float* __restrict__ h,
    const int* __restrict__ rowptr, const int* __restrict__ esrc, const float* __restrict__ eattr,
    const float* __restrict__ TIN, const int* __restrict__ flag,
    const float* __restrict__ root_w, const float* __restrict__ conv_b,
    const float* __restrict__ WI, const float* __restrict__ WH, const float* __restrict__ BS,
    const float* __restrict__ MP, const float* __restrict__ MM,
    const float* __restrict__ e2b, const float* __restrict__ e2w,
    const float* __restrict__ e1w, const float* __restrict__ e1b,
    float* __restrict__ TOUT, int N, int computeT)
{
    __shared__ float sm[XGR + 2304];
    int tid = threadIdx.x;
    int fast = flag[0];
    {
        float4* s4 = (float4*)sm;
        const float4* r4  = (const float4*)root_w;
        const float4* wh4 = (const float4*)WH;
        const float4* wi4 = (const float4*)WI;
        for (int i = tid; i < 256; i += 256) s4[i] = r4[i];
        for (int i = tid; i < 768; i += 256) s4[256  + i] = wh4[i];
        for (int i = tid; i < 768; i += 256) s4[1024 + i] = wi4[i];
        if (computeT && fast) {
            for (int i = tid; i < 768; i += 256) {
                const float4* src = (i < 256) ? (const float4*)MP
                                  : (i < 512) ? (const float4*)MM
                                              : (const float4*)e2b;
                s4[1792 + i] = src[i & 255];
            }
        }
    }
    __syncthreads();

    int lane = tid & 63;
    int w = tid >> 6;
    int fg = lane & 7, fg4 = fg*4;
    int nw = lane >> 3;
    int n0 = (blockIdx.x * 4 + w) * 16 + nw * 2;
    int n1 = n0 + 1;
    bool v0 = (n0 < N), v1 = (n1 < N);
    int nc0 = v0 ? n0 : (N - 1);
    int nc1 = v1 ? n1 : (N - 1);
    int xb0 = XGR + w*576 + nw*72;
    int xb1 = xb0 + 36;

    float4 h0 = *(const float4*)&h[nc0*32 + fg4];
    float4 h1 = *(const float4*)&h[nc1*32 + fg4];
    float hold0[4] = {h0.x, h0.y, h0.z, h0.w};
    float hold1[4] = {h1.x, h1.y, h1.z, h1.w};
    *(float4*)&sm[xb0 + fg4] = h0;        // publish h rows (wave-local, lockstep)
    *(float4*)&sm[xb1 + fg4] = h1;

    // ---- CSR gather: dual independent chains (2 edges in flight per lane) ----
    float av0[4] = {0.f,0.f,0.f,0.f};
    float av1[4] = {0.f,0.f,0.f,0.f};
    {
        int j0 = rowptr[nc0], e0 = rowptr[nc0 + 1];
        int j1 = rowptr[nc1], e1 = rowptr[nc1 + 1];
        if (fast) {
            while (j0 < e0 && j1 < e1) {
                int s0 = esrc[j0];  float a0 = eattr[j0];
                int s1 = esrc[j1];  float a1 = eattr[j1];
                const float* p0 = TIN + (size_t)s0 * 96;
                const float* p1 = TIN + (size_t)s1 * 96;
                float4 q0 = *(const float4*)&p0[(a0 > 0.f ? 0 : 32) + fg4];
                float4 r0 = *(const float4*)&p0[64 + fg4];
                float4 q1 = *(const float4*)&p1[(a1 > 0.f ? 0 : 32) + fg4];
                float4 r1 = *(const float4*)&p1[64 + fg4];
                av0[0] += fmaf(a0, q0.x, r0.x); av0[1] += fmaf(a0, q0.y, r0.y);
                av0[2] += fmaf(a0, q0.z, r0.z); av0[3] += fmaf(a0, q0.w, r0.w);
                av1[0] += fmaf(a1, q1.x, r1.x); av1[1] += fmaf(a1, q1.y, r1.y);
                av1[2] += fmaf(a1, q1.z, r1.z); av1[3] += fmaf(a1, q1.w, r1.w);
                ++j0; ++j1;
            }
            while (j0 < e0) {
                int s0 = esrc[j0];  float a0 = eattr[j0];
                const float* p0 = TIN + (size_t)s0 * 96;
                float4 q0 = *(const float4*)&p0[(a0 > 0.f ? 0 : 32) + fg4];
                float4 r0 = *(const float4*)&p0[64 + fg4];
                av0[0] += fmaf(a0, q0.x, r0.x); av0[1] += fmaf(a0, q0.y, r0.y);
                av0[2] += fmaf(a0, q0.z, r0.z); av0[3] += fmaf(a0, q0.w, r0.w);
                ++j0;
            }
            while (j1 < e1) {
                int s1 = esrc[j1];  float a1 = eattr[j1];
                const float* p1 = TIN + (size_t)s1 * 96;
                float4 q1 = *(const float4*)&p1[(a1 > 0.f ? 0 : 32) + fg4];
                float4 r1 = *(const float4*)&p1[64 + fg4];
                av1[0] += fmaf(a1, q1.x, r1.x); av1[1] += fmaf(a1, q1.y, r1.y);
                av1[2] += fmaf(a1, q1.z, r1.z); av1[3] += fmaf(a1, q1.w, r1.w);
                ++j1;
            }
        } else {
            for (int j = j0; j < e0; ++j) {
                int src = esrc[j];  float a = eattr[j];
                const float* Gp = TIN + (size_t)src * 288;
                float4 b = *(const float4*)&Gp[256 + fg4];
                float m0 = b.x, m1 = b.y, m2 = b.z, m3 = b.w;
                #pragma unroll
                for (int k = 0; k < 8; ++k) {
                    float t = fmaxf(fmaf(a, e1w[k], e1b[k]), 0.f);
                    float4 g = *(const float4*)&Gp[k*32 + fg4];
                    m0 = fmaf(t, g.x, m0); m1 = fmaf(t, g.y, m1);
                    m2 = fmaf(t, g.z, m2); m3 = fmaf(t, g.w, m3);
                }
                av0[0] += m0; av0[1] += m1; av0[2] += m2; av0[3] += m3;
            }
            for (int j = j1; j < e1; ++j) {
                int src = esrc[j];  float a = eattr[j];
                const float* Gp = TIN + (size_t)src * 288;
                float4 b = *(const float4*)&Gp[256 + fg4];
                float m0 = b.x, m1 = b.y, m2 = b.z, m3 = b.w;
                #pragma unroll
                for (int k = 0; k < 8; ++k) {
                    float t = fmaxf(fmaf(a, e1w[k], e1b[k]), 0.f);
                    float4 g = *(const float4*)&Gp[k*32 + fg4];
                    m0 = fmaf(t, g.x, m0); m1 = fmaf(t, g.y, m1);
                    m2 = fmaf(t, g.z, m2); m3 = fmaf(t, g.w, m3);
                }
                av1[0] += m0; av1[1] += m1; av1[2] += m2; av1[3] += m3;
            }
        }
    }

    // ---- out_pre = agg + conv_b + h@root_w ; gh2 = bh2 + h@WH2 (both nodes) ----
    float outv0[4], outv1[4], gh2_0[4], gh2_1[4];
    {
        float4 cb4 = *(const float4*)&conv_b[fg4];
        outv0[0]=av0[0]+cb4.x; outv0[1]=av0[1]+cb4.y; outv0[2]=av0[2]+cb4.z; outv0[3]=av0[3]+cb4.w;
        outv1[0]=av1[0]+cb4.x; outv1[1]=av1[1]+cb4.y; outv1[2]=av1[2]+cb4.z; outv1[3]=av1[3]+cb4.w;
        float4 b3 = *(const float4*)&BS[96 + fg4];
        gh2_0[0]=b3.x; gh2_0[1]=b3.y; gh2_0[2]=b3.z; gh2_0[3]=b3.w;
        gh2_1[0]=b3.x; gh2_1[1]=b3.y; gh2_1[2]=b3.z; gh2_1[3]=b3.w;
    }
    pass2_lds2(sm, xb0, xb1, 0, 1024 + 2048, fg4, outv0, gh2_0, outv1, gh2_1);

    float gh0_0[4]={0.f,0.f,0.f,0.f}, gh1_0[4]={0.f,0.f,0.f,0.f};
    float gh0_1[4]={0.f,0.f,0.f,0.f}, gh1_1[4]={0.f,0.f,0.f,0.f};
    pass2_lds2(sm, xb0, xb1, 1024, 2048, fg4, gh0_0, gh1_0, gh0_1, gh1_1);

    float outr0[4], outr1[4];
    #pragma unroll
    for (int j = 0; j < 4; ++j) {
        outr0[j] = fmaxf(outv0[j], 0.f);
        outr1[j] = fmaxf(outv1[j], 0.f);
    }
    *(float4*)&sm[xb0 + fg4] = make_float4(outr0[0], outr0[1], outr0[2], outr0[3]);
    *(float4*)&sm[xb1 + fg4] = make_float4(outr1[0], outr1[1], outr1[2], outr1[3]);

    float gi0_0[4], gi1_0[4], gi2_0[4];
    float gi0_1[4], gi1_1[4], gi2_1[4];
    {
        float4 b0 = *(const float4*)&BS[fg4];
        float4 b1 = *(const float4*)&BS[32 + fg4];
        float4 b2 = *(const float4*)&BS[64 + fg4];
        gi0_0[0]=b0.x; gi0_0[1]=b0.y; gi0_0[2]=b0.z; gi0_0[3]=b0.w;
        gi0_1[0]=b0.x; gi0_1[1]=b0.y; gi0_1[2]=b0.z; gi0_1[3]=b0.w;
        gi1_0[0]=b1.x; gi1_0[1]=b1.y; gi1_0[2]=b1.z; gi1_0[3]=b1.w;
        gi1_1[0]=b1.x; gi1_1[1]=b1.y; gi1_1[2]=b1.z; gi1_1[3]=b1.w;
        gi2_0[0]=b2.x; gi2_0[1]=b2.y; gi2_0[2]=b2.z; gi2_0[3]=b2.w;
        gi2_1[0]=b2.x; gi2_1[1]=b2.y; gi2_1[2]=b2.z; gi2_1[3]=b2.w;
    }
    pass2_lds2(sm, xb0, xb1, 4096, 5120, fg4, gi0_0, gi1_0, gi0_1, gi1_1);
    pass1_lds2(sm, xb0, xb1, 6144, fg4, gi2_0, gi2_1);

    float hnew0[4], hnew1[4];
    #pragma unroll
    for (int j = 0; j < 4; ++j) {
        float r0 = sigmoidf_(gi0_0[j] + gh0_0[j]);
        float z0 = sigmoidf_(gi1_0[j] + gh1_0[j]);
        float nn0 = tanhf(gi2_0[j] + r0 * gh2_0[j]);
        hnew0[j] = (1.f - z0) * nn0 + z0 * hold0[j];
        float r1 = sigmoidf_(gi0_1[j] + gh0_1[j]);
        float z1 = sigmoidf_(gi1_1[j] + gh1_1[j]);
        float nn1 = tanhf(gi2_1[j] + r1 * gh2_1[j]);
        hnew1[j] = (1.f - z1) * nn1 + z1 * hold1[j];
    }
    if (v0) *(float4*)&h[n0*32 + fg4] = make_float4(hnew0[0], hnew0[1], hnew0[2], hnew0[3]);
    if (v1) *(float4*)&h[n1*32 + fg4] = make_float4(hnew1[0], hnew1[1], hnew1[2], hnew1[3]);

    // ---- next-iteration table into TOUT (MW pre-staged at kernel top; no extra barriers) ----
    if (computeT) {
        *(float4*)&sm[xb0 + fg4] = make_float4(hnew0[0], hnew0[1], hnew0[2], hnew0[3]);
        *(float4*)&sm[xb1 + fg4] = make_float4(hnew1[0], hnew1[1], hnew1[2], hnew1[3]);
        if (fast) {
            #pragma unroll 1
            for (int cc = 0; cc < 3; ++cc) {
                float acc0[4] = {0.f,0.f,0.f,0.f};
                float acc1[4] = {0.f,0.f,0.f,0.f};
                pass1_lds2(sm, xb0, xb1, 7168 + cc*1024, fg4, acc0, acc1);
                if (v0)
                    *(float4*)&TOUT[(size_t)n0*96 + cc*32 + fg4] =
                        make_float4(acc0[0], acc0[1], acc0[2], acc0[3]);
                if (v1)
                    *(float4*)&TOUT[(size_t)n1*96 + cc*32 + fg4] =
                        make_float4(acc1[0], acc1[1], acc1[2], acc1[3]);
            }
        } else {
            #pragma unroll 1
            for (int cg = 0; cg < 3; ++cg) {
                __syncthreads();
                float4* s4 = (float4*)sm;
                for (int i = tid; i < 768; i += 256) {
                    int c = cg*3 + (i >> 8);
                    const float4* src = (c < 8) ? (const float4*)(e2w + (size_t)c*1024)
                                                : (const float4*)e2b;
                    s4[1792 + i] = src[i & 255];
                }
                __syncthreads();
                #pragma unroll 1
                for (int cc = 0; cc < 3; ++cc) {
                    float acc0[4] = {0.f,0.f,0.f,0.f};
                    float acc1[4] = {0.f,0.f,0.f,0.f};
                    pass1_lds2(sm, xb0, xb1, 7168 + cc*1024, fg4, acc0, acc1);
                    if (v0)
                        *(float4*)&TOUT[(size_t)n0*288 + (cg*3+cc)*32 + fg4] =
                            make_float4(acc0[0], acc0[1], acc0[2], acc0[3]);
                    if (v1)
                        *(float4*)&TOUT[(size_t)n1*288 + (cg*3+cc)*32 + fg4] =
                            make_float4(acc1[0], acc1[1], acc1[2], acc1[3]);
                }
            }
        }
    }
}

// ---------------- readout pass1: e[n] = h[n]·q, segment max ----------------
__global__ __launch_bounds__(256) void k_pass1(
    const float* __restrict__ h, const int* __restrict__ batch,
    const float* __restrict__ qvec, float* __restrict__ ebuf,
    unsigned int* __restrict__ segmax, int N)
{
    int b = blockIdx.x / CHUNKS;
    int c = blockIdx.x % CHUNKS;
    int lo = 0, hi = N;
    while (lo < hi) { int mid = (lo + hi) >> 1; if (batch[mid] < b) lo = mid + 1; else hi = mid; }
    int s = lo;
    lo = 0; hi = N;
    while (lo < hi) { int mid = (lo + hi) >> 1; if (batch[mid] < b + 1) lo = mid + 1; else hi = mid; }
    int e = lo;
    int len = e - s;
    int per = (len + CHUNKS - 1) / CHUNKS;
    int n0 = s + c * per;
    int n1 = min(n0 + per, e);

    int tid = threadIdx.x;
    int ln = tid >> 5, o = tid & 31;
    float qv = qvec[o];
    float mloc = -INFINITY;
    for (int nn = n0 + ln; nn < n1; nn += 8) {
        float v = h[nn * H + o] * qv;
        #pragma unroll
        for (int m = 16; m >= 1; m >>= 1) v += __shfl_xor(v, m);
        if (o == 0) ebuf[nn] = v;
        mloc = fmaxf(mloc, v);
    }
    __shared__ float red[256];
    red[tid] = mloc;
    __syncthreads();
    for (int st = 128; st >= 1; st >>= 1) {
        if (tid < st) red[tid] = fmaxf(red[tid], red[tid + st]);
        __syncthreads();
    }
    if (tid == 0 && n0 < n1) atomicMax(&segmax[b], fenc(red[0]));
}

// ---------------- readout pass2: a = exp(e - emax); vsum += a*h; ssum += a ----------------
__global__ __launch_bounds__(256) void k_pass2(
    const float* __restrict__ h, const int* __restrict__ batch,
    const float* __restrict__ ebuf, const unsigned int* __restrict__ segmax,
    float* __restrict__ ssum, float* __restrict__ vsum, int N)
{
    int b = blockIdx.x / CHUNKS;
    int c = blockIdx.x % CHUNKS;
    int lo = 0, hi = N;
    while (lo < hi) { int mid = (lo + hi) >> 1; if (batch[mid] < b) lo = mid + 1; else hi = mid; }
    int s = lo;
    lo = 0; hi = N;
    while (lo < hi) { int mid = (lo + hi) >> 1; if (batch[mid] < b + 1) lo = mid + 1; else hi = mid; }
    int e = lo;
    int len = e - s;
    int per = (len + CHUNKS - 1) / CHUNKS;
    int n0 = s + c * per;
    int n1 = min(n0 + per, e);

    int tid = threadIdx.x;
    int ln = tid >> 5, o = tid & 31;
    float emax = fdec(segmax[b]);
    float vacc = 0.f, sacc = 0.f;
    for (int nn = n0 + ln; nn < n1; nn += 8) {
        float a = expf(ebuf[nn] - emax);
        vacc += a * h[nn * H + o];
        if (o == 0) sacc += a;
    }
    __shared__ float vsh[8][H];
    __shared__ float ssh[8];
    vsh[ln][o] = vacc;
    if (o == 0) ssh[ln] = sacc;
    __syncthreads();
    if (tid < H) {
        float v = 0.f;
        #pragma unroll
        for (int g = 0; g < 8; ++g) v += vsh[g][tid];
        atomicAdd(&vsum[b * H + tid], v);
    } else if (tid == H) {
        float stot = 0.f;
        #pragma unroll
        for (int g = 0; g < 8; ++g) stot += ssh[g];
        atomicAdd(&ssum[b], stot);
    }
}

// ---------------- final MLP on (16, 64) ----------------
__global__ __launch_bounds__(512) void k_mlp(
    const float* __restrict__ qvec, const float* __restrict__ ssum, const float* __restrict__ vsum,
    const float* __restrict__ f1w, const float* __restrict__ f1b,
    const float* __restrict__ f2w, const float* __restrict__ f2b,
    const float* __restrict__ f3w, const float* __restrict__ f3b,
    float* __restrict__ out)
{
    __shared__ float qsm[BSEG][2 * H];
    __shared__ float o1[BSEG][H];
    __shared__ float o2[BSEG][H];
    int tid = threadIdx.x;
    int b = tid >> 5, j = tid & 31;
    float st = ssum[b];
    qsm[b][j] = qvec[j];
    qsm[b][H + j] = (st > 0.f) ? vsum[b * H + j] / st : 0.f;
    __syncthreads();
    float acc = f1b[j];
    for (int i = 0; i < 2 * H; ++i) acc += qsm[b][i] * f1w[i * H + j];
    o1[b][j] = fmaxf(acc, 0.f);
    __syncthreads();
    acc = f2b[j];
    for (int i = 0; i < H; ++i) acc += o1[b][i] * f2w[i * H + j];
    o2[b][j] = fmaxf(acc, 0.f);
    __syncthreads();
    float v = o2[b][j] * f3w[j];
    #pragma unroll
    for (int m = 16; m >= 1; m >>= 1) v += __shfl_xor(v, m);
    if (j == 0) out[b] = v + f3b[0];
}

extern "C" void kernel_launch(void* const* d_in, const int* in_sizes, int n_in,
                              void* d_out, int out_size, void* d_ws, size_t ws_size,
                              hipStream_t stream)
{
    const float* x      = (const float*)d_in[0];
    const int*   ei     = (const int*)d_in[1];
    const float* ea     = (const float*)d_in[2];
    const int*   batch  = (const int*)d_in[3];
    const float* proj_w = (const float*)d_in[4];
    const float* proj_b = (const float*)d_in[5];
    const float* e1w    = (const float*)d_in[6];
    const float* e1b    = (const float*)d_in[7];
    const float* e2w    = (const float*)d_in[8];
    const float* e2b    = (const float*)d_in[9];
    const float* root_w = (const float*)d_in[10];
    const float* conv_b = (const float*)d_in[11];
    const float* gru_wi = (const float*)d_in[12];
    const float* gru_wh = (const float*)d_in[13];
    const float* gru_bi = (const float*)d_in[14];
    const float* gru_bh = (const float*)d_in[15];
    const float* lstm_bi = (const float*)d_in[18];
    const float* lstm_bh = (const float*)d_in[19];
    const float* f1w    = (const float*)d_in[20];
    const float* f1b    = (const float*)d_in[21];
    const float* f2w    = (const float*)d_in[22];
    const float* f2b    = (const float*)d_in[23];
    const float* f3w    = (const float*)d_in[24];
    const float* f3b    = (const float*)d_in[25];

    const int N = in_sizes[0] / 4;
    const int E = in_sizes[2];

    float* ws   = (float*)d_ws;
    float* h    = ws;                        // N*32
    float* A    = h + (size_t)N * H;         // N*288 (ping)
    float* Bb   = A + (size_t)N * 288;       // N*288 (pong)
    float* ebuf = Bb + (size_t)N * 288;      // N
    float* qvec = ebuf + N;                  // 32
    unsigned int* segmax = (unsigned int*)(qvec + H);  // 16
    float* ssum = (float*)(segmax + BSEG);   // 16
    float* vsum = ssum + BSEG;               // 512
    float* WI   = vsum + BSEG * H;           // 3072
    float* WH   = WI + 3072;                 // 3072
    float* BS   = WH + 3072;                 // 128
    float* MP   = BS + 128;                  // 1024
    float* MM   = MP + 1024;                 // 1024
    int*   flag = (int*)(MM + 1024);         // 1
    int*   cnt    = flag + 1;                // N
    int*   rowptr = cnt + N;                 // N+1
    int*   cursor = rowptr + N + 1;          // N
    int*   esrc   = cursor + N;              // E
    float* eattr  = (float*)(esrc + E);      // E

    const int nwaves = (N + 7) / 8;          // 8 nodes per wave (k_tab)
    const int nb4 = (nwaves + 3) / 4;        // 4 waves per block
    const int gb  = (N + 63) / 64;           // k_gru: 16 nodes/wave x 4 waves
    const int cblocks = (E + 255) / 256;

    k_prep<<<1, 512, 0, stream>>>(gru_wi, gru_wh, gru_bi, gru_bh, lstm_bi, lstm_bh,
                                  e1w, e1b, e2w,
                                  WI, WH, BS, MP, MM, flag, qvec, segmax, ssum, vsum, cnt, N);
    k_count<<<cblocks, 256, 0, stream>>>(ei, cnt, E);
    k_scan<<<1, 1024, 0, stream>>>(cnt, rowptr, cursor, N);
    k_scatter<<<cblocks, 256, 0, stream>>>(ei, ea, cursor, esrc, eattr, E);
    k_tab<<<nb4, 256, 0, stream>>>(x, proj_w, proj_b, e2w, e2b, MP, MM, flag, h, A, N);

    k_gru<<<gb, 256, 0, stream>>>(h, rowptr, esrc, eattr, A, flag, root_w, conv_b,
                                  WI, WH, BS, MP, MM, e2b, e2w, e1w, e1b, Bb, N, 1);
    k_gru<<<gb, 256, 0, stream>>>(h, rowptr, esrc, eattr, Bb, flag, root_w, conv_b,
                                  WI, WH, BS, MP, MM, e2b, e2w, e1w, e1b, A, N, 1);
    k_gru<<<gb, 256, 0, stream>>>(h, rowptr, esrc, eattr, A, flag, root_w, conv_b,
                                  WI, WH, BS, MP, MM, e2b, e2w, e1w, e1b, Bb, N, 0);

    k_pass1<<<BSEG * CHUNKS, 256, 0, stream>>>(h, batch, qvec, ebuf, segmax, N);
    k_pass2<<<BSEG * CHUNKS, 256, 0, stream>>>(h, batch, ebuf, segmax, ssum, vsum, N);
    k_mlp<<<1, 512, 0, stream>>>(qvec, ssum, vsum, f1w, f1b, f2w, f2b, f3w, f3b, (float*)d_out);
}

// Round 14
// 181.869 us; speedup vs baseline: 1.1609x; 1.1609x over previous
//
#include <hip/hip_runtime.h>
#include <math.h>

#define H 32
#define BSEG 16
#define CHUNKS 32

#define FMA4(acc, s, wv) { acc[0]=fmaf(s,wv.x,acc[0]); acc[1]=fmaf(s,wv.y,acc[1]); acc[2]=fmaf(s,wv.z,acc[2]); acc[3]=fmaf(s,wv.w,acc[3]); }

__device__ __forceinline__ float sigmoidf_(float x){ return 1.f/(1.f+expf(-x)); }

__device__ __forceinline__ unsigned int fenc(float f) {
    int i = __float_as_int(f);
    return (i >= 0) ? ((unsigned int)i | 0x80000000u) : ~(unsigned int)i;
}
__device__ __forceinline__ float fdec(unsigned int u) {
    int i = (u & 0x80000000u) ? (int)(u & 0x7FFFFFFFu) : (int)(~u);
    return __int_as_float(i);
}

// ---------------- prep: transposed GRU weights, fused biases, qvec, masked edge matrices, zero cnt ----------------
__global__ __launch_bounds__(512) void k_prep(
    const float* __restrict__ gru_wi, const float* __restrict__ gru_wh,
    const float* __restrict__ gru_bi, const float* __restrict__ gru_bh,
    const float* __restrict__ lstm_bi, const float* __restrict__ lstm_bh,
    const float* __restrict__ e1w, const float* __restrict__ e1b, const float* __restrict__ e2w,
    float* __restrict__ WI, float* __restrict__ WH, float* __restrict__ BS,
    float* __restrict__ MP, float* __restrict__ MM, int* __restrict__ flag,
    float* __restrict__ qvec, unsigned int* __restrict__ segmax,
    float* __restrict__ ssum, float* __restrict__ vsum,
    int* __restrict__ cnt, int N)
{
    int t = threadIdx.x;
    for (int i = t; i < N; i += 512) cnt[i] = 0;
    for (int idx = t; idx < 3072; idx += 512) {
        int k = idx >> 10, rem = idx & 1023, i = rem >> 5, o = rem & 31;
        WI[idx] = gru_wi[(k*32 + o)*32 + i];
        WH[idx] = gru_wh[(k*32 + o)*32 + i];
    }
    for (int idx = t; idx < 1024; idx += 512) {
        float mp = 0.f, mm = 0.f;
        #pragma unroll
        for (int k = 0; k < 8; ++k) {
            float w = e1w[k];
            float v = e2w[k*1024 + idx];
            if (w > 0.f) mp = fmaf(w, v, mp);
            if (w < 0.f) mm = fmaf(w, v, mm);
        }
        MP[idx] = mp;
        MM[idx] = mm;
    }
    if (t == 0) {
        int z = 1;
        for (int k = 0; k < 8; ++k) if (e1b[k] != 0.f) z = 0;
        flag[0] = z;
    }
    if (t < 32) {
        BS[t]      = gru_bi[t]      + gru_bh[t];
        BS[32 + t] = gru_bi[32 + t] + gru_bh[32 + t];
        BS[64 + t] = gru_bi[64 + t];
        BS[96 + t] = gru_bh[64 + t];
    }
    if (t < H) {
        float g0 = lstm_bi[t] + lstm_bh[t];
        float g2 = lstm_bi[2*H + t] + lstm_bh[2*H + t];
        float g3 = lstm_bi[3*H + t] + lstm_bh[3*H + t];
        float ig = sigmoidf_(g0);
        float gg = tanhf(g2);
        float og = sigmoidf_(g3);
        qvec[t] = og * tanhf(ig * gg);
    }
    for (int i = t; i < BSEG; i += 512) { segmax[i] = 0u; ssum[i] = 0.f; }
    for (int i = t; i < BSEG*H; i += 512) vsum[i] = 0.f;
}

// ---------------- CSR build: count -> scan -> scatter ----------------
__global__ __launch_bounds__(256) void k_count(const int* __restrict__ ei, int* __restrict__ cnt, int E)
{
    int e = blockIdx.x * 256 + threadIdx.x;
    if (e < E) atomicAdd(&cnt[ei[E + e]], 1);
}

__global__ __launch_bounds__(1024) void k_scan(
    const int* __restrict__ cnt, int* __restrict__ rowptr, int* __restrict__ cursor, int N)
{
    __shared__ int part[1024];
    int t = threadIdx.x;
    int chunk = (N + 1023) >> 10;
    int base = t * chunk;
    int s = 0;
    for (int i = 0; i < chunk; ++i) {
        int idx = base + i;
        if (idx < N) s += cnt[idx];
    }
    part[t] = s;
    __syncthreads();
    for (int off = 1; off < 1024; off <<= 1) {
        int add = (t >= off) ? part[t - off] : 0;
        __syncthreads();
        part[t] += add;
        __syncthreads();
    }
    int run = part[t] - s;                 // exclusive prefix for this chunk
    for (int i = 0; i < chunk; ++i) {
        int idx = base + i;
        if (idx < N) {
            rowptr[idx] = run;
            cursor[idx] = run;
            run += cnt[idx];
        }
    }
    if (t == 1023) rowptr[N] = part[1023];
}

__global__ __launch_bounds__(256) void k_scatter(
    const int* __restrict__ ei, const float* __restrict__ ea, int* __restrict__ cursor,
    int* __restrict__ esrc, float* __restrict__ eattr, int E)
{
    int e = blockIdx.x * 256 + threadIdx.x;
    if (e >= E) return;
    int dst = ei[E + e];
    int pos = atomicAdd(&cursor[dst], 1);
    esrc[pos] = ei[e];
    eattr[pos] = ea[e];
}

// ---- LDS-based K=32 passes (x row broadcast across node's 8 fg-lanes; weights across 8 node-lanes) ----
__device__ __forceinline__ void pass2_lds(const float* sm, int xb, int w0, int w1, int fg4,
                                          float a[4], float b[4])
{
    #pragma unroll 2
    for (int i4 = 0; i4 < 32; i4 += 4) {
        float4 xv  = *(const float4*)&sm[xb + i4];
        float4 w00 = *(const float4*)&sm[w0 + (i4+0)*32 + fg4];
        float4 w01 = *(const float4*)&sm[w0 + (i4+1)*32 + fg4];
        float4 w02 = *(const float4*)&sm[w0 + (i4+2)*32 + fg4];
        float4 w03 = *(const float4*)&sm[w0 + (i4+3)*32 + fg4];
        float4 w10 = *(const float4*)&sm[w1 + (i4+0)*32 + fg4];
        float4 w11 = *(const float4*)&sm[w1 + (i4+1)*32 + fg4];
        float4 w12 = *(const float4*)&sm[w1 + (i4+2)*32 + fg4];
        float4 w13 = *(const float4*)&sm[w1 + (i4+3)*32 + fg4];
        FMA4(a, xv.x, w00) FMA4(a, xv.y, w01) FMA4(a, xv.z, w02) FMA4(a, xv.w, w03)
        FMA4(b, xv.x, w10) FMA4(b, xv.y, w11) FMA4(b, xv.z, w12) FMA4(b, xv.w, w13)
    }
}

__device__ __forceinline__ void pass1_lds(const float* sm, int xb, int w0, int fg4, float a[4])
{
    #pragma unroll 2
    for (int i4 = 0; i4 < 32; i4 += 4) {
        float4 xv  = *(const float4*)&sm[xb + i4];
        float4 w00 = *(const float4*)&sm[w0 + (i4+0)*32 + fg4];
        float4 w01 = *(const float4*)&sm[w0 + (i4+1)*32 + fg4];
        float4 w02 = *(const float4*)&sm[w0 + (i4+2)*32 + fg4];
        float4 w03 = *(const float4*)&sm[w0 + (i4+3)*32 + fg4];
        FMA4(a, xv.x, w00) FMA4(a, xv.y, w01) FMA4(a, xv.z, w02) FMA4(a, xv.w, w03)
    }
}

// ---------------- tab: proj fused + initial table. fast: T[n] stride 96; fallback: G[n] stride 288 ----------------
#define TW 3072
__global__ __launch_bounds__(256, 2) void k_tab(
    const float* __restrict__ x, const float* __restrict__ proj_w, const float* __restrict__ proj_b,
    const float* __restrict__ e2w, const float* __restrict__ e2b,
    const float* __restrict__ MP, const float* __restrict__ MM, const int* __restrict__ flag,
    float* __restrict__ h, float* __restrict__ A, int N)
{
    __shared__ float sm[TW + 4*288];
    int tid = threadIdx.x;
    int lane = tid & 63;
    int w = tid >> 6;
    int fg = lane & 7, fg4 = fg*4;
    int nw = lane >> 3;
    int n = (blockIdx.x * 4 + w) * 8 + nw;
    bool valid = (n < N);
    int nc = valid ? n : (N - 1);
    int xb = TW + w*288 + nw*36;

    // proj fused: h row for this node
    {
        float4 xv = *(const float4*)&x[nc*4];
        float r_[4];
        #pragma unroll
        for (int j = 0; j < 4; ++j) {
            int o = fg4 + j;
            float a = proj_b[o];
            a = fmaf(xv.x, proj_w[0*32 + o], a);
            a = fmaf(xv.y, proj_w[1*32 + o], a);
            a = fmaf(xv.z, proj_w[2*32 + o], a);
            a = fmaf(xv.w, proj_w[3*32 + o], a);
            r_[j] = fmaxf(a, 0.f);
        }
        if (valid) *(float4*)&h[n*32 + fg4] = make_float4(r_[0], r_[1], r_[2], r_[3]);
        *(float4*)&sm[xb + fg4] = make_float4(r_[0], r_[1], r_[2], r_[3]);
    }

    if (flag[0]) {
        float4* s4 = (float4*)sm;
        for (int i = tid; i < 768; i += 256) {
            const float4* src = (i < 256) ? (const float4*)MP
                              : (i < 512) ? (const float4*)MM
                                          : (const float4*)e2b;
            s4[i] = src[i & 255];
        }
        __syncthreads();
        #pragma unroll 1
        for (int cc = 0; cc < 3; ++cc) {
            float acc[4] = {0.f, 0.f, 0.f, 0.f};
            pass1_lds(sm, xb, cc*1024, fg4, acc);
            if (valid)
                *(float4*)&A[(size_t)n*96 + cc*32 + fg4] =
                    make_float4(acc[0], acc[1], acc[2], acc[3]);
        }
    } else {
        #pragma unroll 1
        for (int cg = 0; cg < 3; ++cg) {
            __syncthreads();
            float4* s4 = (float4*)sm;
            for (int i = tid; i < 768; i += 256) {
                int c = cg*3 + (i >> 8);
                const float4* src = (c < 8) ? (const float4*)(e2w + (size_t)c*1024)
                                            : (const float4*)e2b;
                s4[i] = src[i & 255];
            }
            __syncthreads();
            #pragma unroll 1
            for (int cc = 0; cc < 3; ++cc) {
                float acc[4] = {0.f, 0.f, 0.f, 0.f};
                pass1_lds(sm, xb, cc*1024, fg4, acc);
                if (valid)
                    *(float4*)&A[(size_t)n*288 + (cg*3+cc)*32 + fg4] =
                        make_float4(acc[0], acc[1], acc[2], acc[3]);
            }
        }
    }
}

// ---------------- fused iteration (R12 structure): CSR gather (4-wide MLP) -> GRU -> h; next-table ----------------
// LDS floats: ROOT[0,1024) WH[1024,4096) WI[4096,7168) MW[7168,10240) X[10240,+1152)
#define XGR 10240
__global__ __launch_bounds__(256, 2) void k_gru(
    float* __restrict__ h,
    const int* __restrict__ rowptr, const int* __restrict__ esrc, const float* __restrict__ eattr,
    const float* __restrict__ TIN, const int* __restrict__ flag,
    const float* __restrict__ root_w, const float* __restrict__ conv_b,
    const float* __restrict__ WI, const float* __restrict__ WH, const float* __restrict__ BS,
    const float* __restrict__ MP, const float* __restrict__ MM,
    const float* __restrict__ e2b, const float* __restrict__ e2w,
    const float* __restrict__ e1w, const float* __restrict__ e1b,
    float* __restrict__ TOUT, int N, int computeT)
{
    __shared__ float sm[XGR + 1152];
    int tid = threadIdx.x;
    int fast = flag[0];
    {
        float4* s4 = (float4*)sm;
        const float4* r4  = (const float4*)root_w;
        const float4* wh4 = (const float4*)WH;
        const float4* wi4 = (const float4*)WI;
        for (int i = tid; i < 256; i += 256) s4[i] = r4[i];
        for (int i = tid; i < 768; i += 256) s4[256  + i] = wh4[i];
        for (int i = tid; i < 768; i += 256) s4[1024 + i] = wi4[i];
        if (computeT && fast) {
            for (int i = tid; i < 768; i += 256) {
                const float4* src = (i < 256) ? (const float4*)MP
                                  : (i < 512) ? (const float4*)MM
                                              : (const float4*)e2b;
                s4[1792 + i] = src[i & 255];
            }
        }
    }
    __syncthreads();

    int lane = tid & 63;
    int w = tid >> 6;
    int fg = lane & 7, fg4 = fg*4;
    int nw = lane >> 3;
    int n = (blockIdx.x * 4 + w) * 8 + nw;
    bool valid = (n < N);
    int nc = valid ? n : (N - 1);
    int xb = XGR + w*288 + nw*36;

    float4 hv4 = *(const float4*)&h[nc*32 + fg4];
    float hold[4] = {hv4.x, hv4.y, hv4.z, hv4.w};
    *(float4*)&sm[xb + fg4] = hv4;        // publish h row (wave-local)

    // ---- CSR gather: 4-wide batched loads (8 T-row loads in flight per lane) ----
    float av[4] = {0.f, 0.f, 0.f, 0.f};
    {
        int beg = rowptr[nc];
        int end = rowptr[nc + 1];
        if (fast) {
            int j = beg;
            for (; j + 3 < end; j += 4) {
                int s0 = esrc[j],     s1 = esrc[j + 1];
                int s2 = esrc[j + 2], s3 = esrc[j + 3];
                float a0 = eattr[j],     a1 = eattr[j + 1];
                float a2 = eattr[j + 2], a3 = eattr[j + 3];
                const float* p0 = TIN + (size_t)s0 * 96;
                const float* p1 = TIN + (size_t)s1 * 96;
                const float* p2 = TIN + (size_t)s2 * 96;
                const float* p3 = TIN + (size_t)s3 * 96;
                float4 q0 = *(const float4*)&p0[(a0 > 0.f ? 0 : 32) + fg4];
                float4 r0 = *(const float4*)&p0[64 + fg4];
                float4 q1 = *(const float4*)&p1[(a1 > 0.f ? 0 : 32) + fg4];
                float4 r1 = *(const float4*)&p1[64 + fg4];
                float4 q2 = *(const float4*)&p2[(a2 > 0.f ? 0 : 32) + fg4];
                float4 r2 = *(const float4*)&p2[64 + fg4];
                float4 q3 = *(const float4*)&p3[(a3 > 0.f ? 0 : 32) + fg4];
                float4 r3 = *(const float4*)&p3[64 + fg4];
                av[0] += fmaf(a0, q0.x, r0.x) + fmaf(a1, q1.x, r1.x)
                       + fmaf(a2, q2.x, r2.x) + fmaf(a3, q3.x, r3.x);
                av[1] += fmaf(a0, q0.y, r0.y) + fmaf(a1, q1.y, r1.y)
                       + fmaf(a2, q2.y, r2.y) + fmaf(a3, q3.y, r3.y);
                av[2] += fmaf(a0, q0.z, r0.z) + fmaf(a1, q1.z, r1.z)
                       + fmaf(a2, q2.z, r2.z) + fmaf(a3, q3.z, r3.z);
                av[3] += fmaf(a0, q0.w, r0.w) + fmaf(a1, q1.w, r1.w)
                       + fmaf(a2, q2.w, r2.w) + fmaf(a3, q3.w, r3.w);
            }
            for (; j < end; ++j) {
                int s0 = esrc[j];
                float a0 = eattr[j];
                const float* p0 = TIN + (size_t)s0 * 96;
                float4 q0 = *(const float4*)&p0[(a0 > 0.f ? 0 : 32) + fg4];
                float4 r0 = *(const float4*)&p0[64 + fg4];
                av[0] += fmaf(a0, q0.x, r0.x);
                av[1] += fmaf(a0, q0.y, r0.y);
                av[2] += fmaf(a0, q0.z, r0.z);
                av[3] += fmaf(a0, q0.w, r0.w);
            }
        } else {
            for (int j = beg; j < end; ++j) {
                int src = esrc[j];
                float a = eattr[j];
                const float* Gp = TIN + (size_t)src * 288;
                float4 b = *(const float4*)&Gp[256 + fg4];
                float m0 = b.x, m1 = b.y, m2 = b.z, m3 = b.w;
                #pragma unroll
                for (int k = 0; k < 8; ++k) {
                    float t = fmaxf(fmaf(a, e1w[k], e1b[k]), 0.f);
                    float4 g = *(const float4*)&Gp[k*32 + fg4];
                    m0 = fmaf(t, g.x, m0); m1 = fmaf(t, g.y, m1);
                    m2 = fmaf(t, g.z, m2); m3 = fmaf(t, g.w, m3);
                }
                av[0] += m0; av[1] += m1; av[2] += m2; av[3] += m3;
            }
        }
    }

    // ---- out_pre = agg + conv_b + h@root_w ; gh2 = bh2 + h@WH2 ----
    float outv[4], gh2[4];
    {
        float4 cb4 = *(const float4*)&conv_b[fg4];
        outv[0]=av[0]+cb4.x; outv[1]=av[1]+cb4.y; outv[2]=av[2]+cb4.z; outv[3]=av[3]+cb4.w;
        float4 b3 = *(const float4*)&BS[96 + fg4];
        gh2[0]=b3.x; gh2[1]=b3.y; gh2[2]=b3.z; gh2[3]=b3.w;
    }
    pass2_lds(sm, xb, 0, 1024 + 2048, fg4, outv, gh2);

    float gh0[4] = {0.f,0.f,0.f,0.f};
    float gh1[4] = {0.f,0.f,0.f,0.f};
    pass2_lds(sm, xb, 1024, 2048, fg4, gh0, gh1);

    float outr[4];
    #pragma unroll
    for (int j = 0; j < 4; ++j) outr[j] = fmaxf(outv[j], 0.f);

    *(float4*)&sm[xb + fg4] = make_float4(outr[0], outr[1], outr[2], outr[3]);

    float gi0[4], gi1[4], gi2[4];
    {
        float4 b0 = *(const float4*)&BS[fg4];
        float4 b1 = *(const float4*)&BS[32 + fg4];
        float4 b2 = *(const float4*)&BS[64 + fg4];
        gi0[0]=b0.x; gi0[1]=b0.y; gi0[2]=b0.z; gi0[3]=b0.w;
        gi1[0]=b1.x; gi1[1]=b1.y; gi1[2]=b1.z; gi1[3]=b1.w;
        gi2[0]=b2.x; gi2[1]=b2.y; gi2[2]=b2.z; gi2[3]=b2.w;
    }
    pass2_lds(sm, xb, 4096, 5120, fg4, gi0, gi1);
    pass1_lds(sm, xb, 6144, fg4, gi2);

    float hnew[4];
    #pragma unroll
    for (int j = 0; j < 4; ++j) {
        float r = sigmoidf_(gi0[j] + gh0[j]);
        float z = sigmoidf_(gi1[j] + gh1[j]);
        float nn = tanhf(gi2[j] + r * gh2[j]);
        hnew[j] = (1.f - z) * nn + z * hold[j];
    }
    if (valid) *(float4*)&h[n*32 + fg4] = make_float4(hnew[0], hnew[1], hnew[2], hnew[3]);

    // ---- next-iteration table into TOUT (MW pre-staged at kernel top; no extra barriers) ----
    if (computeT) {
        *(float4*)&sm[xb + fg4] = make_float4(hnew[0], hnew[1], hnew[2], hnew[3]);
        if (fast) {
            #pragma unroll 1
            for (int cc = 0; cc < 3; ++cc) {
                float acc[4] = {0.f, 0.f, 0.f, 0.f};
                pass1_lds(sm, xb, 7168 + cc*1024, fg4, acc);
                if (valid)
                    *(float4*)&TOUT[(size_t)n*96 + cc*32 + fg4] =
                        make_float4(acc[0], acc[1], acc[2], acc[3]);
            }
        } else {
            #pragma unroll 1
            for (int cg = 0; cg < 3; ++cg) {
                __syncthreads();
                float4* s4 = (float4*)sm;
                for (int i = tid; i < 768; i += 256) {
                    int c = cg*3 + (i >> 8);
                    const float4* src = (c < 8) ? (const float4*)(e2w + (size_t)c*1024)
                                                : (const float4*)e2b;
                    s4[1792 + i] = src[i & 255];
                }
                __syncthreads();
                #pragma unroll 1
                for (int cc = 0; cc < 3; ++cc) {
                    float acc[4] = {0.f, 0.f, 0.f, 0.f};
                    pass1_lds(sm, xb, 7168 + cc*1024, fg4, acc);
                    if (valid)
                        *(float4*)&TOUT[(size_t)n*288 + (cg*3+cc)*32 + fg4] =
                            make_float4(acc[0], acc[1], acc[2], acc[3]);
                }
            }
        }
    }
}

// ---------------- readout pass1: e[n] = h[n]·q, segment max ----------------
__global__ __launch_bounds__(256) void k_pass1(
    const float* __restrict__ h, const int* __restrict__ batch,
    const float* __restrict__ qvec, float* __restrict__ ebuf,
    unsigned int* __restrict__ segmax, int N)
{
    int b = blockIdx.x / CHUNKS;
    int c = blockIdx.x % CHUNKS;
    int lo = 0, hi = N;
    while (lo < hi) { int mid = (lo + hi) >> 1; if (batch[mid] < b) lo = mid + 1; else hi = mid; }
    int s = lo;
    lo = 0; hi = N;
    while (lo < hi) { int mid = (lo + hi) >> 1; if (batch[mid] < b + 1) lo = mid + 1; else hi = mid; }
    int e = lo;
    int len = e - s;
    int per = (len + CHUNKS - 1) / CHUNKS;
    int n0 = s + c * per;
    int n1 = min(n0 + per, e);

    int tid = threadIdx.x;
    int ln = tid >> 5, o = tid & 31;
    float qv = qvec[o];
    float mloc = -INFINITY;
    for (int nn = n0 + ln; nn < n1; nn += 8) {
        float v = h[nn * H + o] * qv;
        #pragma unroll
        for (int m = 16; m >= 1; m >>= 1) v += __shfl_xor(v, m);
        if (o == 0) ebuf[nn] = v;
        mloc = fmaxf(mloc, v);
    }
    __shared__ float red[256];
    red[tid] = mloc;
    __syncthreads();
    for (int st = 128; st >= 1; st >>= 1) {
        if (tid < st) red[tid] = fmaxf(red[tid], red[tid + st]);
        __syncthreads();
    }
    if (tid == 0 && n0 < n1) atomicMax(&segmax[b], fenc(red[0]));
}

// ---------------- readout pass2: a = exp(e - emax); vsum += a*h; ssum += a ----------------
__global__ __launch_bounds__(256) void k_pass2(
    const float* __restrict__ h, const int* __restrict__ batch,
    const float* __restrict__ ebuf, const unsigned int* __restrict__ segmax,
    float* __restrict__ ssum, float* __restrict__ vsum, int N)
{
    int b = blockIdx.x / CHUNKS;
    int c = blockIdx.x % CHUNKS;
    int lo = 0, hi = N;
    while (lo < hi) { int mid = (lo + hi) >> 1; if (batch[mid] < b) lo = mid + 1; else hi = mid; }
    int s = lo;
    lo = 0; hi = N;
    while (lo < hi) { int mid = (lo + hi) >> 1; if (batch[mid] < b + 1) lo = mid + 1; else hi = mid; }
    int e = lo;
    int len = e - s;
    int per = (len + CHUNKS - 1) / CHUNKS;
    int n0 = s + c * per;
    int n1 = min(n0 + per, e);

    int tid = threadIdx.x;
    int ln = tid >> 5, o = tid & 31;
    float emax = fdec(segmax[b]);
    float vacc = 0.f, sacc = 0.f;
    for (int nn = n0 + ln; nn < n1; nn += 8) {
        float a = expf(ebuf[nn] - emax);
        vacc += a * h[nn * H + o];
        if (o == 0) sacc += a;
    }
    __shared__ float vsh[8][H];
    __shared__ float ssh[8];
    vsh[ln][o] = vacc;
    if (o == 0) ssh[ln] = sacc;
    __syncthreads();
    if (tid < H) {
        float v = 0.f;
        #pragma unroll
        for (int g = 0; g < 8; ++g) v += vsh[g][tid];
        atomicAdd(&vsum[b * H + tid], v);
    } else if (tid == H) {
        float stot = 0.f;
        #pragma unroll
        for (int g = 0; g < 8; ++g) stot += ssh[g];
        atomicAdd(&ssum[b], stot);
    }
}

// ---------------- final MLP on (16, 64) ----------------
__global__ __launch_bounds__(512) void k_mlp(
    const float* __restrict__ qvec, const float* __restrict__ ssum, const float* __restrict__ vsum,
    const float* __restrict__ f1w, const float* __restrict__ f1b,
    const float* __restrict__ f2w, const float* __restrict__ f2b,
    const float* __restrict__ f3w, const float* __restrict__ f3b,
    float* __restrict__ out)
{
    __shared__ float qsm[BSEG][2 * H];
    __shared__ float o1[BSEG][H];
    __shared__ float o2[BSEG][H];
    int tid = threadIdx.x;
    int b = tid >> 5, j = tid & 31;
    float st = ssum[b];
    qsm[b][j] = qvec[j];
    qsm[b][H + j] = (st > 0.f) ? vsum[b * H + j] / st : 0.f;
    __syncthreads();
    float acc = f1b[j];
    for (int i = 0; i < 2 * H; ++i) acc += qsm[b][i] * f1w[i * H + j];
    o1[b][j] = fmaxf(acc, 0.f);
    __syncthreads();
    acc = f2b[j];
    for (int i = 0; i < H; ++i) acc += o1[b][i] * f2w[i * H + j];
    o2[b][j] = fmaxf(acc, 0.f);
    __syncthreads();
    float v = o2[b][j] * f3w[j];
    #pragma unroll
    for (int m = 16; m >= 1; m >>= 1) v += __shfl_xor(v, m);
    if (j == 0) out[b] = v + f3b[0];
}

extern "C" void kernel_launch(void* const* d_in, const int* in_sizes, int n_in,
                              void* d_out, int out_size, void* d_ws, size_t ws_size,
                              hipStream_t stream)
{
    const float* x      = (const float*)d_in[0];
    const int*   ei     = (const int*)d_in[1];
    const float* ea     = (const float*)d_in[2];
    const int*   batch  = (const int*)d_in[3];
    const float* proj_w = (const float*)d_in[4];
    const float* proj_b = (const float*)d_in[5];
    const float* e1w    = (const float*)d_in[6];
    const float* e1b    = (const float*)d_in[7];
    const float* e2w    = (const float*)d_in[8];
    const float* e2b    = (const float*)d_in[9];
    const float* root_w = (const float*)d_in[10];
    const float* conv_b = (const float*)d_in[11];
    const float* gru_wi = (const float*)d_in[12];
    const float* gru_wh = (const float*)d_in[13];
    const float* gru_bi = (const float*)d_in[14];
    const float* gru_bh = (const float*)d_in[15];
    const float* lstm_bi = (const float*)d_in[18];
    const float* lstm_bh = (const float*)d_in[19];
    const float* f1w    = (const float*)d_in[20];
    const float* f1b    = (const float*)d_in[21];
    const float* f2w    = (const float*)d_in[22];
    const float* f2b    = (const float*)d_in[23];
    const float* f3w    = (const float*)d_in[24];
    const float* f3b    = (const float*)d_in[25];

    const int N = in_sizes[0] / 4;
    const int E = in_sizes[2];

    float* ws   = (float*)d_ws;
    float* h    = ws;                        // N*32
    float* A    = h + (size_t)N * H;         // N*288 (ping)
    float* Bb   = A + (size_t)N * 288;       // N*288 (pong)
    float* ebuf = Bb + (size_t)N * 288;      // N
    float* qvec = ebuf + N;                  // 32
    unsigned int* segmax = (unsigned int*)(qvec + H);  // 16
    float* ssum = (float*)(segmax + BSEG);   // 16
    float* vsum = ssum + BSEG;               // 512
    float* WI   = vsum + BSEG * H;           // 3072
    float* WH   = WI + 3072;                 // 3072
    float* BS   = WH + 3072;                 // 128
    float* MP   = BS + 128;                  // 1024
    float* MM   = MP + 1024;                 // 1024
    int*   flag = (int*)(MM + 1024);         // 1
    int*   cnt    = flag + 1;                // N
    int*   rowptr = cnt + N;                 // N+1
    int*   cursor = rowptr + N + 1;          // N
    int*   esrc   = cursor + N;              // E
    float* eattr  = (float*)(esrc + E);      // E

    const int nwaves = (N + 7) / 8;          // 8 nodes per wave
    const int nb4 = (nwaves + 3) / 4;        // 4 waves per block
    const int cblocks = (E + 255) / 256;

    k_prep<<<1, 512, 0, stream>>>(gru_wi, gru_wh, gru_bi, gru_bh, lstm_bi, lstm_bh,
                                  e1w, e1b, e2w,
                                  WI, WH, BS, MP, MM, flag, qvec, segmax, ssum, vsum, cnt, N);
    k_count<<<cblocks, 256, 0, stream>>>(ei, cnt, E);
    k_scan<<<1, 1024, 0, stream>>>(cnt, rowptr, cursor, N);
    k_scatter<<<cblocks, 256, 0, stream>>>(ei, ea, cursor, esrc, eattr, E);
    k_tab<<<nb4, 256, 0, stream>>>(x, proj_w, proj_b, e2w, e2b, MP, MM, flag, h, A, N);

    k_gru<<<nb4, 256, 0, stream>>>(h, rowptr, esrc, eattr, A, flag, root_w, conv_b,
                                   WI, WH, BS, MP, MM, e2b, e2w, e1w, e1b, Bb, N, 1);
    k_gru<<<nb4, 256, 0, stream>>>(h, rowptr, esrc, eattr, Bb, flag, root_w, conv_b,
                                   WI, WH, BS, MP, MM, e2b, e2w, e1w, e1b, A, N, 1);
    k_gru<<<nb4, 256, 0, stream>>>(h, rowptr, esrc, eattr, A, flag, root_w, conv_b,
                                   WI, WH, BS, MP, MM, e2b, e2w, e1w, e1b, Bb, N, 0);

    k_pass1<<<BSEG * CHUNKS, 256, 0, stream>>>(h, batch, qvec, ebuf, segmax, N);
    k_pass2<<<BSEG * CHUNKS, 256, 0, stream>>>(h, batch, ebuf, segmax, ssum, vsum, N);
    k_mlp<<<1, 512, 0, stream>>>(qvec, ssum, vsum, f1w, f1b, f2w, f2b, f3w, f3b, (float*)d_out);
}

// Round 15
// 167.948 us; speedup vs baseline: 1.2572x; 1.0829x over previous
//
#include <hip/hip_runtime.h>
#include <math.h>

#define H 32
#define BSEG 16
#define CHUNKS 32

#define FMA4(acc, s, wv) { acc[0]=fmaf(s,wv.x,acc[0]); acc[1]=fmaf(s,wv.y,acc[1]); acc[2]=fmaf(s,wv.z,acc[2]); acc[3]=fmaf(s,wv.w,acc[3]); }

__device__ __forceinline__ float sigmoidf_(float x){ return 1.f/(1.f+expf(-x)); }

__device__ __forceinline__ unsigned int fenc(float f) {
    int i = __float_as_int(f);
    return (i >= 0) ? ((unsigned int)i | 0x80000000u) : ~(unsigned int)i;
}
__device__ __forceinline__ float fdec(unsigned int u) {
    int i = (u & 0x80000000u) ? (int)(u & 0x7FFFFFFFu) : (int)(~u);
    return __int_as_float(i);
}

// ---------------- prep: transposed GRU weights, fused biases, qvec, masked edge matrices, zero cnt ----------------
__global__ __launch_bounds__(512) void k_prep(
    const float* __restrict__ gru_wi, const float* __restrict__ gru_wh,
    const float* __restrict__ gru_bi, const float* __restrict__ gru_bh,
    const float* __restrict__ lstm_bi, const float* __restrict__ lstm_bh,
    const float* __restrict__ e1w, const float* __restrict__ e1b, const float* __restrict__ e2w,
    float* __restrict__ WI, float* __restrict__ WH, float* __restrict__ BS,
    float* __restrict__ MP, float* __restrict__ MM, int* __restrict__ flag,
    float* __restrict__ qvec, unsigned int* __restrict__ segmax,
    float* __restrict__ ssum, float* __restrict__ vsum,
    int* __restrict__ cnt, int N)
{
    int t = threadIdx.x;
    for (int i = t; i < N; i += 512) cnt[i] = 0;
    for (int idx = t; idx < 3072; idx += 512) {
        int k = idx >> 10, rem = idx & 1023, i = rem >> 5, o = rem & 31;
        WI[idx] = gru_wi[(k*32 + o)*32 + i];
        WH[idx] = gru_wh[(k*32 + o)*32 + i];
    }
    for (int idx = t; idx < 1024; idx += 512) {
        float mp = 0.f, mm = 0.f;
        #pragma unroll
        for (int k = 0; k < 8; ++k) {
            float w = e1w[k];
            float v = e2w[k*1024 + idx];
            if (w > 0.f) mp = fmaf(w, v, mp);
            if (w < 0.f) mm = fmaf(w, v, mm);
        }
        MP[idx] = mp;
        MM[idx] = mm;
    }
    if (t == 0) {
        int z = 1;
        for (int k = 0; k < 8; ++k) if (e1b[k] != 0.f) z = 0;
        flag[0] = z;
    }
    if (t < 32) {
        BS[t]      = gru_bi[t]      + gru_bh[t];
        BS[32 + t] = gru_bi[32 + t] + gru_bh[32 + t];
        BS[64 + t] = gru_bi[64 + t];
        BS[96 + t] = gru_bh[64 + t];
    }
    if (t < H) {
        float g0 = lstm_bi[t] + lstm_bh[t];
        float g2 = lstm_bi[2*H + t] + lstm_bh[2*H + t];
        float g3 = lstm_bi[3*H + t] + lstm_bh[3*H + t];
        float ig = sigmoidf_(g0);
        float gg = tanhf(g2);
        float og = sigmoidf_(g3);
        qvec[t] = og * tanhf(ig * gg);
    }
    for (int i = t; i < BSEG; i += 512) { segmax[i] = 0u; ssum[i] = 0.f; }
    for (int i = t; i < BSEG*H; i += 512) vsum[i] = 0.f;
}

// ---------------- CSR build: count -> scan -> scatter ----------------
__global__ __launch_bounds__(256) void k_count(const int* __restrict__ ei, int* __restrict__ cnt, int E)
{
    int e = blockIdx.x * 256 + threadIdx.x;
    if (e < E) atomicAdd(&cnt[ei[E + e]], 1);
}

__global__ __launch_bounds__(1024) void k_scan(
    const int* __restrict__ cnt, int* __restrict__ rowptr, int* __restrict__ cursor, int N)
{
    __shared__ int part[1024];
    int t = threadIdx.x;
    int chunk = (N + 1023) >> 10;
    int base = t * chunk;
    int s = 0;
    for (int i = 0; i < chunk; ++i) {
        int idx = base + i;
        if (idx < N) s += cnt[idx];
    }
    part[t] = s;
    __syncthreads();
    for (int off = 1; off < 1024; off <<= 1) {
        int add = (t >= off) ? part[t - off] : 0;
        __syncthreads();
        part[t] += add;
        __syncthreads();
    }
    int run = part[t] - s;                 // exclusive prefix for this chunk
    for (int i = 0; i < chunk; ++i) {
        int idx = base + i;
        if (idx < N) {
            rowptr[idx] = run;
            cursor[idx] = run;
            run += cnt[idx];
        }
    }
    if (t == 1023) rowptr[N] = part[1023];
}

__global__ __launch_bounds__(256) void k_scatter(
    const int* __restrict__ ei, const float* __restrict__ ea, int* __restrict__ cursor,
    int* __restrict__ esrc, float* __restrict__ eattr, int E)
{
    int e = blockIdx.x * 256 + threadIdx.x;
    if (e >= E) return;
    int dst = ei[E + e];
    int pos = atomicAdd(&cursor[dst], 1);
    esrc[pos] = ei[e];
    eattr[pos] = ea[e];
}

// ---- LDS-based K=32 passes (x row broadcast across node's 8 fg-lanes; weights across 8 node-lanes) ----
__device__ __forceinline__ void pass2_lds(const float* sm, int xb, int w0, int w1, int fg4,
                                          float a[4], float b[4])
{
    #pragma unroll 2
    for (int i4 = 0; i4 < 32; i4 += 4) {
        float4 xv  = *(const float4*)&sm[xb + i4];
        float4 w00 = *(const float4*)&sm[w0 + (i4+0)*32 + fg4];
        float4 w01 = *(const float4*)&sm[w0 + (i4+1)*32 + fg4];
        float4 w02 = *(const float4*)&sm[w0 + (i4+2)*32 + fg4];
        float4 w03 = *(const float4*)&sm[w0 + (i4+3)*32 + fg4];
        float4 w10 = *(const float4*)&sm[w1 + (i4+0)*32 + fg4];
        float4 w11 = *(const float4*)&sm[w1 + (i4+1)*32 + fg4];
        float4 w12 = *(const float4*)&sm[w1 + (i4+2)*32 + fg4];
        float4 w13 = *(const float4*)&sm[w1 + (i4+3)*32 + fg4];
        FMA4(a, xv.x, w00) FMA4(a, xv.y, w01) FMA4(a, xv.z, w02) FMA4(a, xv.w, w03)
        FMA4(b, xv.x, w10) FMA4(b, xv.y, w11) FMA4(b, xv.z, w12) FMA4(b, xv.w, w13)
    }
}

__device__ __forceinline__ void pass1_lds(const float* sm, int xb, int w0, int fg4, float a[4])
{
    #pragma unroll 2
    for (int i4 = 0; i4 < 32; i4 += 4) {
        float4 xv  = *(const float4*)&sm[xb + i4];
        float4 w00 = *(const float4*)&sm[w0 + (i4+0)*32 + fg4];
        float4 w01 = *(const float4*)&sm[w0 + (i4+1)*32 + fg4];
        float4 w02 = *(const float4*)&sm[w0 + (i4+2)*32 + fg4];
        float4 w03 = *(const float4*)&sm[w0 + (i4+3)*32 + fg4];
        FMA4(a, xv.x, w00) FMA4(a, xv.y, w01) FMA4(a, xv.z, w02) FMA4(a, xv.w, w03)
    }
}

// ---------------- tab: proj (writes h). fallback additionally builds G table (stride 288) ----------------
#define TW 3072
__global__ __launch_bounds__(256, 2) void k_tab(
    const float* __restrict__ x, const float* __restrict__ proj_w, const float* __restrict__ proj_b,
    const float* __restrict__ e2w, const float* __restrict__ e2b,
    const int* __restrict__ flag,
    float* __restrict__ h, float* __restrict__ A, int N)
{
    __shared__ float sm[TW + 4*288];
    int tid = threadIdx.x;
    int lane = tid & 63;
    int w = tid >> 6;
    int fg = lane & 7, fg4 = fg*4;
    int nw = lane >> 3;
    int n = (blockIdx.x * 4 + w) * 8 + nw;
    bool valid = (n < N);
    int nc = valid ? n : (N - 1);
    int xb = TW + w*288 + nw*36;

    // proj: h row for this node
    {
        float4 xv = *(const float4*)&x[nc*4];
        float r_[4];
        #pragma unroll
        for (int j = 0; j < 4; ++j) {
            int o = fg4 + j;
            float a = proj_b[o];
            a = fmaf(xv.x, proj_w[0*32 + o], a);
            a = fmaf(xv.y, proj_w[1*32 + o], a);
            a = fmaf(xv.z, proj_w[2*32 + o], a);
            a = fmaf(xv.w, proj_w[3*32 + o], a);
            r_[j] = fmaxf(a, 0.f);
        }
        if (valid) *(float4*)&h[n*32 + fg4] = make_float4(r_[0], r_[1], r_[2], r_[3]);
        *(float4*)&sm[xb + fg4] = make_float4(r_[0], r_[1], r_[2], r_[3]);
    }

    if (!flag[0]) {
        // fallback: build G table for edge gather
        #pragma unroll 1
        for (int cg = 0; cg < 3; ++cg) {
            __syncthreads();
            float4* s4 = (float4*)sm;
            for (int i = tid; i < 768; i += 256) {
                int c = cg*3 + (i >> 8);
                const float4* src = (c < 8) ? (const float4*)(e2w + (size_t)c*1024)
                                            : (const float4*)e2b;
                s4[i] = src[i & 255];
            }
            __syncthreads();
            #pragma unroll 1
            for (int cc = 0; cc < 3; ++cc) {
                float acc[4] = {0.f, 0.f, 0.f, 0.f};
                pass1_lds(sm, xb, cc*1024, fg4, acc);
                if (valid)
                    *(float4*)&A[(size_t)n*288 + (cg*3+cc)*32 + fg4] =
                        make_float4(acc[0], acc[1], acc[2], acc[3]);
            }
        }
    }
}

// ---------------- fused iteration: u-vector gather from hIN -> agg GEMVs -> GRU -> hOUT ----------------
// Fast path: agg = u+@MP + u-@MM + u0@e2b (exact for e1b==0); no T table at all.
// LDS floats: ROOT[0,1024) WH[1024,4096) WI[4096,7168) MW[7168,10240) X[10240,+1152)
#define XGR 10240
__global__ __launch_bounds__(256, 2) void k_gru(
    const float* __restrict__ hIN, float* __restrict__ hOUT,
    const int* __restrict__ rowptr, const int* __restrict__ esrc, const float* __restrict__ eattr,
    const float* __restrict__ TIN, const int* __restrict__ flag,
    const float* __restrict__ root_w, const float* __restrict__ conv_b,
    const float* __restrict__ WI, const float* __restrict__ WH, const float* __restrict__ BS,
    const float* __restrict__ MP, const float* __restrict__ MM,
    const float* __restrict__ e2b, const float* __restrict__ e2w,
    const float* __restrict__ e1w, const float* __restrict__ e1b,
    float* __restrict__ TOUT, int N, int computeT)
{
    __shared__ float sm[XGR + 1152];
    int tid = threadIdx.x;
    int fast = flag[0];
    {
        float4* s4 = (float4*)sm;
        const float4* r4  = (const float4*)root_w;
        const float4* wh4 = (const float4*)WH;
        const float4* wi4 = (const float4*)WI;
        for (int i = tid; i < 256; i += 256) s4[i] = r4[i];
        for (int i = tid; i < 768; i += 256) s4[256  + i] = wh4[i];
        for (int i = tid; i < 768; i += 256) s4[1024 + i] = wi4[i];
        if (fast) {
            // MW = MP | MM | e2b  (needed every iteration for the u-vector GEMVs)
            for (int i = tid; i < 768; i += 256) {
                const float4* src = (i < 256) ? (const float4*)MP
                                  : (i < 512) ? (const float4*)MM
                                              : (const float4*)e2b;
                s4[1792 + i] = src[i & 255];
            }
        }
    }
    __syncthreads();

    int lane = tid & 63;
    int w = tid >> 6;
    int fg = lane & 7, fg4 = fg*4;
    int nw = lane >> 3;
    int n = (blockIdx.x * 4 + w) * 8 + nw;
    bool valid = (n < N);
    int nc = valid ? n : (N - 1);
    int xb = XGR + w*288 + nw*36;

    float4 hv4 = *(const float4*)&hIN[nc*32 + fg4];
    float hold[4] = {hv4.x, hv4.y, hv4.z, hv4.w};

    float av[4] = {0.f, 0.f, 0.f, 0.f};
    if (fast) {
        // ---- u-vector gather: 1 float4 load per edge per lane (half of T-row gather) ----
        float up[4] = {0.f,0.f,0.f,0.f};
        float um[4] = {0.f,0.f,0.f,0.f};
        float u0[4] = {0.f,0.f,0.f,0.f};
        int beg = rowptr[nc];
        int end = rowptr[nc + 1];
        int j = beg;
        for (; j + 3 < end; j += 4) {
            int s0 = esrc[j],     s1 = esrc[j + 1];
            int s2 = esrc[j + 2], s3 = esrc[j + 3];
            float a0 = eattr[j],     a1 = eattr[j + 1];
            float a2 = eattr[j + 2], a3 = eattr[j + 3];
            float4 g0 = *(const float4*)&hIN[(size_t)s0*32 + fg4];
            float4 g1 = *(const float4*)&hIN[(size_t)s1*32 + fg4];
            float4 g2 = *(const float4*)&hIN[(size_t)s2*32 + fg4];
            float4 g3 = *(const float4*)&hIN[(size_t)s3*32 + fg4];
            float p0 = fmaxf(a0, 0.f), m0 = fminf(a0, 0.f);
            float p1 = fmaxf(a1, 0.f), m1 = fminf(a1, 0.f);
            float p2 = fmaxf(a2, 0.f), m2 = fminf(a2, 0.f);
            float p3 = fmaxf(a3, 0.f), m3 = fminf(a3, 0.f);
            FMA4(up, p0, g0) FMA4(up, p1, g1) FMA4(up, p2, g2) FMA4(up, p3, g3)
            FMA4(um, m0, g0) FMA4(um, m1, g1) FMA4(um, m2, g2) FMA4(um, m3, g3)
            u0[0] += g0.x + g1.x + g2.x + g3.x;
            u0[1] += g0.y + g1.y + g2.y + g3.y;
            u0[2] += g0.z + g1.z + g2.z + g3.z;
            u0[3] += g0.w + g1.w + g2.w + g3.w;
        }
        for (; j < end; ++j) {
            int s0 = esrc[j];
            float a0 = eattr[j];
            float4 g0 = *(const float4*)&hIN[(size_t)s0*32 + fg4];
            float p0 = fmaxf(a0, 0.f), m0 = fminf(a0, 0.f);
            FMA4(up, p0, g0)
            FMA4(um, m0, g0)
            u0[0] += g0.x; u0[1] += g0.y; u0[2] += g0.z; u0[3] += g0.w;
        }
        // ---- agg = up@MP + um@MM + u0@e2b via sequential wave-local row publishes ----
        *(float4*)&sm[xb + fg4] = make_float4(up[0], up[1], up[2], up[3]);
        pass1_lds(sm, xb, 7168, fg4, av);
        *(float4*)&sm[xb + fg4] = make_float4(um[0], um[1], um[2], um[3]);
        pass1_lds(sm, xb, 8192, fg4, av);
        *(float4*)&sm[xb + fg4] = make_float4(u0[0], u0[1], u0[2], u0[3]);
        pass1_lds(sm, xb, 9216, fg4, av);
    } else {
        // fallback: 9-row G gather (e1b != 0), exact
        int beg = rowptr[nc];
        int end = rowptr[nc + 1];
        for (int j = beg; j < end; ++j) {
            int src = esrc[j];
            float a = eattr[j];
            const float* Gp = TIN + (size_t)src * 288;
            float4 b = *(const float4*)&Gp[256 + fg4];
            float m0 = b.x, m1 = b.y, m2 = b.z, m3 = b.w;
            #pragma unroll
            for (int k = 0; k < 8; ++k) {
                float t = fmaxf(fmaf(a, e1w[k], e1b[k]), 0.f);
                float4 g = *(const float4*)&Gp[k*32 + fg4];
                m0 = fmaf(t, g.x, m0); m1 = fmaf(t, g.y, m1);
                m2 = fmaf(t, g.z, m2); m3 = fmaf(t, g.w, m3);
            }
            av[0] += m0; av[1] += m1; av[2] += m2; av[3] += m3;
        }
    }

    // ---- publish h row; out_pre = agg + conv_b + h@root_w ; gh2 = bh2 + h@WH2 ----
    *(float4*)&sm[xb + fg4] = hv4;
    float outv[4], gh2[4];
    {
        float4 cb4 = *(const float4*)&conv_b[fg4];
        outv[0]=av[0]+cb4.x; outv[1]=av[1]+cb4.y; outv[2]=av[2]+cb4.z; outv[3]=av[3]+cb4.w;
        float4 b3 = *(const float4*)&BS[96 + fg4];
        gh2[0]=b3.x; gh2[1]=b3.y; gh2[2]=b3.z; gh2[3]=b3.w;
    }
    pass2_lds(sm, xb, 0, 1024 + 2048, fg4, outv, gh2);

    float gh0[4] = {0.f,0.f,0.f,0.f};
    float gh1[4] = {0.f,0.f,0.f,0.f};
    pass2_lds(sm, xb, 1024, 2048, fg4, gh0, gh1);

    float outr[4];
    #pragma unroll
    for (int j = 0; j < 4; ++j) outr[j] = fmaxf(outv[j], 0.f);

    *(float4*)&sm[xb + fg4] = make_float4(outr[0], outr[1], outr[2], outr[3]);

    float gi0[4], gi1[4], gi2[4];
    {
        float4 b0 = *(const float4*)&BS[fg4];
        float4 b1 = *(const float4*)&BS[32 + fg4];
        float4 b2 = *(const float4*)&BS[64 + fg4];
        gi0[0]=b0.x; gi0[1]=b0.y; gi0[2]=b0.z; gi0[3]=b0.w;
        gi1[0]=b1.x; gi1[1]=b1.y; gi1[2]=b1.z; gi1[3]=b1.w;
        gi2[0]=b2.x; gi2[1]=b2.y; gi2[2]=b2.z; gi2[3]=b2.w;
    }
    pass2_lds(sm, xb, 4096, 5120, fg4, gi0, gi1);
    pass1_lds(sm, xb, 6144, fg4, gi2);

    float hnew[4];
    #pragma unroll
    for (int j = 0; j < 4; ++j) {
        float r = sigmoidf_(gi0[j] + gh0[j]);
        float z = sigmoidf_(gi1[j] + gh1[j]);
        float nn = tanhf(gi2[j] + r * gh2[j]);
        hnew[j] = (1.f - z) * nn + z * hold[j];
    }
    if (valid) *(float4*)&hOUT[n*32 + fg4] = make_float4(hnew[0], hnew[1], hnew[2], hnew[3]);

    // ---- fallback only: recompute G table for next iteration ----
    if (!fast && computeT) {
        *(float4*)&sm[xb + fg4] = make_float4(hnew[0], hnew[1], hnew[2], hnew[3]);
        #pragma unroll 1
        for (int cg = 0; cg < 3; ++cg) {
            __syncthreads();
            float4* s4 = (float4*)sm;
            for (int i = tid; i < 768; i += 256) {
                int c = cg*3 + (i >> 8);
                const float4* src = (c < 8) ? (const float4*)(e2w + (size_t)c*1024)
                                            : (const float4*)e2b;
                s4[1792 + i] = src[i & 255];
            }
            __syncthreads();
            #pragma unroll 1
            for (int cc = 0; cc < 3; ++cc) {
                float acc[4] = {0.f, 0.f, 0.f, 0.f};
                pass1_lds(sm, xb, 7168 + cc*1024, fg4, acc);
                if (valid)
                    *(float4*)&TOUT[(size_t)n*288 + (cg*3+cc)*32 + fg4] =
                        make_float4(acc[0], acc[1], acc[2], acc[3]);
            }
        }
    }
}

// ---------------- readout pass1: e[n] = h[n]·q, segment max ----------------
__global__ __launch_bounds__(256) void k_pass1(
    const float* __restrict__ h, const int* __restrict__ batch,
    const float* __restrict__ qvec, float* __restrict__ ebuf,
    unsigned int* __restrict__ segmax, int N)
{
    int b = blockIdx.x / CHUNKS;
    int c = blockIdx.x % CHUNKS;
    int lo = 0, hi = N;
    while (lo < hi) { int mid = (lo + hi) >> 1; if (batch[mid] < b) lo = mid + 1; else hi = mid; }
    int s = lo;
    lo = 0; hi = N;
    while (lo < hi) { int mid = (lo + hi) >> 1; if (batch[mid] < b + 1) lo = mid + 1; else hi = mid; }
    int e = lo;
    int len = e - s;
    int per = (len + CHUNKS - 1) / CHUNKS;
    int n0 = s + c * per;
    int n1 = min(n0 + per, e);

    int tid = threadIdx.x;
    int ln = tid >> 5, o = tid & 31;
    float qv = qvec[o];
    float mloc = -INFINITY;
    for (int nn = n0 + ln; nn < n1; nn += 8) {
        float v = h[nn * H + o] * qv;
        #pragma unroll
        for (int m = 16; m >= 1; m >>= 1) v += __shfl_xor(v, m);
        if (o == 0) ebuf[nn] = v;
        mloc = fmaxf(mloc, v);
    }
    __shared__ float red[256];
    red[tid] = mloc;
    __syncthreads();
    for (int st = 128; st >= 1; st >>= 1) {
        if (tid < st) red[tid] = fmaxf(red[tid], red[tid + st]);
        __syncthreads();
    }
    if (tid == 0 && n0 < n1) atomicMax(&segmax[b], fenc(red[0]));
}

// ---------------- readout pass2: a = exp(e - emax); vsum += a*h; ssum += a ----------------
__global__ __launch_bounds__(256) void k_pass2(
    const float* __restrict__ h, const int* __restrict__ batch,
    const float* __restrict__ ebuf, const unsigned int* __restrict__ segmax,
    float* __restrict__ ssum, float* __restrict__ vsum, int N)
{
    int b = blockIdx.x / CHUNKS;
    int c = blockIdx.x % CHUNKS;
    int lo = 0, hi = N;
    while (lo < hi) { int mid = (lo + hi) >> 1; if (batch[mid] < b) lo = mid + 1; else hi = mid; }
    int s = lo;
    lo = 0; hi = N;
    while (lo < hi) { int mid = (lo + hi) >> 1; if (batch[mid] < b + 1) lo = mid + 1; else hi = mid; }
    int e = lo;
    int len = e - s;
    int per = (len + CHUNKS - 1) / CHUNKS;
    int n0 = s + c * per;
    int n1 = min(n0 + per, e);

    int tid = threadIdx.x;
    int ln = tid >> 5, o = tid & 31;
    float emax = fdec(segmax[b]);
    float vacc = 0.f, sacc = 0.f;
    for (int nn = n0 + ln; nn < n1; nn += 8) {
        float a = expf(ebuf[nn] - emax);
        vacc += a * h[nn * H + o];
        if (o == 0) sacc += a;
    }
    __shared__ float vsh[8][H];
    __shared__ float ssh[8];
    vsh[ln][o] = vacc;
    if (o == 0) ssh[ln] = sacc;
    __syncthreads();
    if (tid < H) {
        float v = 0.f;
        #pragma unroll
        for (int g = 0; g < 8; ++g) v += vsh[g][tid];
        atomicAdd(&vsum[b * H + tid], v);
    } else if (tid == H) {
        float stot = 0.f;
        #pragma unroll
        for (int g = 0; g < 8; ++g) stot += ssh[g];
        atomicAdd(&ssum[b], stot);
    }
}

// ---------------- final MLP on (16, 64) ----------------
__global__ __launch_bounds__(512) void k_mlp(
    const float* __restrict__ qvec, const float* __restrict__ ssum, const float* __restrict__ vsum,
    const float* __restrict__ f1w, const float* __restrict__ f1b,
    const float* __restrict__ f2w, const float* __restrict__ f2b,
    const float* __restrict__ f3w, const float* __restrict__ f3b,
    float* __restrict__ out)
{
    __shared__ float qsm[BSEG][2 * H];
    __shared__ float o1[BSEG][H];
    __shared__ float o2[BSEG][H];
    int tid = threadIdx.x;
    int b = tid >> 5, j = tid & 31;
    float st = ssum[b];
    qsm[b][j] = qvec[j];
    qsm[b][H + j] = (st > 0.f) ? vsum[b * H + j] / st : 0.f;
    __syncthreads();
    float acc = f1b[j];
    for (int i = 0; i < 2 * H; ++i) acc += qsm[b][i] * f1w[i * H + j];
    o1[b][j] = fmaxf(acc, 0.f);
    __syncthreads();
    acc = f2b[j];
    for (int i = 0; i < H; ++i) acc += o1[b][i] * f2w[i * H + j];
    o2[b][j] = fmaxf(acc, 0.f);
    __syncthreads();
    float v = o2[b][j] * f3w[j];
    #pragma unroll
    for (int m = 16; m >= 1; m >>= 1) v += __shfl_xor(v, m);
    if (j == 0) out[b] = v + f3b[0];
}

extern "C" void kernel_launch(void* const* d_in, const int* in_sizes, int n_in,
                              void* d_out, int out_size, void* d_ws, size_t ws_size,
                              hipStream_t stream)
{
    const float* x      = (const float*)d_in[0];
    const int*   ei     = (const int*)d_in[1];
    const float* ea     = (const float*)d_in[2];
    const int*   batch  = (const int*)d_in[3];
    const float* proj_w = (const float*)d_in[4];
    const float* proj_b = (const float*)d_in[5];
    const float* e1w    = (const float*)d_in[6];
    const float* e1b    = (const float*)d_in[7];
    const float* e2w    = (const float*)d_in[8];
    const float* e2b    = (const float*)d_in[9];
    const float* root_w = (const float*)d_in[10];
    const float* conv_b = (const float*)d_in[11];
    const float* gru_wi = (const float*)d_in[12];
    const float* gru_wh = (const float*)d_in[13];
    const float* gru_bi = (const float*)d_in[14];
    const float* gru_bh = (const float*)d_in[15];
    const float* lstm_bi = (const float*)d_in[18];
    const float* lstm_bh = (const float*)d_in[19];
    const float* f1w    = (const float*)d_in[20];
    const float* f1b    = (const float*)d_in[21];
    const float* f2w    = (const float*)d_in[22];
    const float* f2b    = (const float*)d_in[23];
    const float* f3w    = (const float*)d_in[24];
    const float* f3b    = (const float*)d_in[25];

    const int N = in_sizes[0] / 4;
    const int E = in_sizes[2];

    float* ws   = (float*)d_ws;
    float* hA   = ws;                        // N*32 (ping)
    float* hB   = hA + (size_t)N * H;        // N*32 (pong)
    float* A    = hB + (size_t)N * H;        // N*288 (fallback G ping)
    float* Bb   = A + (size_t)N * 288;       // N*288 (fallback G pong)
    float* ebuf = Bb + (size_t)N * 288;      // N
    float* qvec = ebuf + N;                  // 32
    unsigned int* segmax = (unsigned int*)(qvec + H);  // 16
    float* ssum = (float*)(segmax + BSEG);   // 16
    float* vsum = ssum + BSEG;               // 512
    float* WI   = vsum + BSEG * H;           // 3072
    float* WH   = WI + 3072;                 // 3072
    float* BS   = WH + 3072;                 // 128
    float* MP   = BS + 128;                  // 1024
    float* MM   = MP + 1024;                 // 1024
    int*   flag = (int*)(MM + 1024);         // 1
    int*   cnt    = flag + 1;                // N
    int*   rowptr = cnt + N;                 // N+1
    int*   cursor = rowptr + N + 1;          // N
    int*   esrc   = cursor + N;              // E
    float* eattr  = (float*)(esrc + E);      // E

    const int nwaves = (N + 7) / 8;          // 8 nodes per wave
    const int nb4 = (nwaves + 3) / 4;        // 4 waves per block
    const int cblocks = (E + 255) / 256;

    k_prep<<<1, 512, 0, stream>>>(gru_wi, gru_wh, gru_bi, gru_bh, lstm_bi, lstm_bh,
                                  e1w, e1b, e2w,
                                  WI, WH, BS, MP, MM, flag, qvec, segmax, ssum, vsum, cnt, N);
    k_count<<<cblocks, 256, 0, stream>>>(ei, cnt, E);
    k_scan<<<1, 1024, 0, stream>>>(cnt, rowptr, cursor, N);
    k_scatter<<<cblocks, 256, 0, stream>>>(ei, ea, cursor, esrc, eattr, E);
    k_tab<<<nb4, 256, 0, stream>>>(x, proj_w, proj_b, e2w, e2b, flag, hA, A, N);

    k_gru<<<nb4, 256, 0, stream>>>(hA, hB, rowptr, esrc, eattr, A, flag, root_w, conv_b,
                                   WI, WH, BS, MP, MM, e2b, e2w, e1w, e1b, Bb, N, 1);
    k_gru<<<nb4, 256, 0, stream>>>(hB, hA, rowptr, esrc, eattr, Bb, flag, root_w, conv_b,
                                   WI, WH, BS, MP, MM, e2b, e2w, e1w, e1b, A, N, 1);
    k_gru<<<nb4, 256, 0, stream>>>(hA, hB, rowptr, esrc, eattr, A, flag, root_w, conv_b,
                                   WI, WH, BS, MP, MM, e2b, e2w, e1w, e1b, Bb, N, 0);

    k_pass1<<<BSEG * CHUNKS, 256, 0, stream>>>(hB, batch, qvec, ebuf, segmax, N);
    k_pass2<<<BSEG * CHUNKS, 256, 0, stream>>>(hB, batch, ebuf, segmax, ssum, vsum, N);
    k_mlp<<<1, 512, 0, stream>>>(qvec, ssum, vsum, f1w, f1b, f2w, f2b, f3w, f3b, (float*)d_out);
}

// Round 17
// 167.394 us; speedup vs baseline: 1.2613x; 1.0033x over previous
//
#include <hip/hip_runtime.h>
#include <math.h>

#define H 32
#define BSEG 16
#define CHUNKS 32

#define FMA4(acc, s, wv) { acc[0]=fmaf(s,wv.x,acc[0]); acc[1]=fmaf(s,wv.y,acc[1]); acc[2]=fmaf(s,wv.z,acc[2]); acc[3]=fmaf(s,wv.w,acc[3]); }

__device__ __forceinline__ float sigmoidf_(float x){ return 1.f/(1.f+expf(-x)); }

__device__ __forceinline__ unsigned int fenc(float f) {
    int i = __float_as_int(f);
    return (i >= 0) ? ((unsigned int)i | 0x80000000u) : ~(unsigned int)i;
}
__device__ __forceinline__ float fdec(unsigned int u) {
    int i = (u & 0x80000000u) ? (int)(u & 0x7FFFFFFFu) : (int)(~u);
    return __int_as_float(i);
}

// ---------------- prep: transposed GRU weights, fused biases, qvec, masked edge matrices, zero cnt ----------------
__global__ __launch_bounds__(512) void k_prep(
    const float* __restrict__ gru_wi, const float* __restrict__ gru_wh,
    const float* __restrict__ gru_bi, const float* __restrict__ gru_bh,
    const float* __restrict__ lstm_bi, const float* __restrict__ lstm_bh,
    const float* __restrict__ e1w, const float* __restrict__ e1b, const float* __restrict__ e2w,
    float* __restrict__ WI, float* __restrict__ WH, float* __restrict__ BS,
    float* __restrict__ MP, float* __restrict__ MM, int* __restrict__ flag,
    float* __restrict__ qvec, unsigned int* __restrict__ segmax,
    float* __restrict__ ssum, float* __restrict__ vsum,
    int* __restrict__ cnt, int N)
{
    int t = threadIdx.x;
    for (int i = t; i < N; i += 512) cnt[i] = 0;
    for (int idx = t; idx < 3072; idx += 512) {
        int k = idx >> 10, rem = idx & 1023, i = rem >> 5, o = rem & 31;
        WI[idx] = gru_wi[(k*32 + o)*32 + i];
        WH[idx] = gru_wh[(k*32 + o)*32 + i];
    }
    for (int idx = t; idx < 1024; idx += 512) {
        float mp = 0.f, mm = 0.f;
        #pragma unroll
        for (int k = 0; k < 8; ++k) {
            float w = e1w[k];
            float v = e2w[k*1024 + idx];
            if (w > 0.f) mp = fmaf(w, v, mp);
            if (w < 0.f) mm = fmaf(w, v, mm);
        }
        MP[idx] = mp;
        MM[idx] = mm;
    }
    if (t == 0) {
        int z = 1;
        for (int k = 0; k < 8; ++k) if (e1b[k] != 0.f) z = 0;
        flag[0] = z;
    }
    if (t < 32) {
        BS[t]      = gru_bi[t]      + gru_bh[t];
        BS[32 + t] = gru_bi[32 + t] + gru_bh[32 + t];
        BS[64 + t] = gru_bi[64 + t];
        BS[96 + t] = gru_bh[64 + t];
    }
    if (t < H) {
        float g0 = lstm_bi[t] + lstm_bh[t];
        float g2 = lstm_bi[2*H + t] + lstm_bh[2*H + t];
        float g3 = lstm_bi[3*H + t] + lstm_bh[3*H + t];
        float ig = sigmoidf_(g0);
        float gg = tanhf(g2);
        float og = sigmoidf_(g3);
        qvec[t] = og * tanhf(ig * gg);
    }
    for (int i = t; i < BSEG; i += 512) { segmax[i] = 0u; ssum[i] = 0.f; }
    for (int i = t; i < BSEG*H; i += 512) vsum[i] = 0.f;
}

// ---------------- CSR build: count -> scan -> scatter ----------------
__global__ __launch_bounds__(256) void k_count(const int* __restrict__ ei, int* __restrict__ cnt, int E)
{
    int e = blockIdx.x * 256 + threadIdx.x;
    if (e < E) atomicAdd(&cnt[ei[E + e]], 1);
}

__global__ __launch_bounds__(1024) void k_scan(
    const int* __restrict__ cnt, int* __restrict__ rowptr, int* __restrict__ cursor, int N)
{
    __shared__ int part[1024];
    int t = threadIdx.x;
    int chunk = (N + 1023) >> 10;
    int base = t * chunk;
    int s = 0;
    for (int i = 0; i < chunk; ++i) {
        int idx = base + i;
        if (idx < N) s += cnt[idx];
    }
    part[t] = s;
    __syncthreads();
    for (int off = 1; off < 1024; off <<= 1) {
        int add = (t >= off) ? part[t - off] : 0;
        __syncthreads();
        part[t] += add;
        __syncthreads();
    }
    int run = part[t] - s;                 // exclusive prefix for this chunk
    for (int i = 0; i < chunk; ++i) {
        int idx = base + i;
        if (idx < N) {
            rowptr[idx] = run;
            cursor[idx] = run;
            run += cnt[idx];
        }
    }
    if (t == 1023) rowptr[N] = part[1023];
}

__global__ __launch_bounds__(256) void k_scatter(
    const int* __restrict__ ei, const float* __restrict__ ea, int* __restrict__ cursor,
    int* __restrict__ esrc, float* __restrict__ eattr, int E)
{
    int e = blockIdx.x * 256 + threadIdx.x;
    if (e >= E) return;
    int dst = ei[E + e];
    int pos = atomicAdd(&cursor[dst], 1);
    esrc[pos] = ei[e];
    eattr[pos] = ea[e];
}

// ---- LDS-based K=32 passes (x row broadcast across node's 8 fg-lanes; weights across 8 node-lanes) ----
__device__ __forceinline__ void pass2_lds(const float* sm, int xb, int w0, int w1, int fg4,
                                          float a[4], float b[4])
{
    #pragma unroll 2
    for (int i4 = 0; i4 < 32; i4 += 4) {
        float4 xv  = *(const float4*)&sm[xb + i4];
        float4 w00 = *(const float4*)&sm[w0 + (i4+0)*32 + fg4];
        float4 w01 = *(const float4*)&sm[w0 + (i4+1)*32 + fg4];
        float4 w02 = *(const float4*)&sm[w0 + (i4+2)*32 + fg4];
        float4 w03 = *(const float4*)&sm[w0 + (i4+3)*32 + fg4];
        float4 w10 = *(const float4*)&sm[w1 + (i4+0)*32 + fg4];
        float4 w11 = *(const float4*)&sm[w1 + (i4+1)*32 + fg4];
        float4 w12 = *(const float4*)&sm[w1 + (i4+2)*32 + fg4];
        float4 w13 = *(const float4*)&sm[w1 + (i4+3)*32 + fg4];
        FMA4(a, xv.x, w00) FMA4(a, xv.y, w01) FMA4(a, xv.z, w02) FMA4(a, xv.w, w03)
        FMA4(b, xv.x, w10) FMA4(b, xv.y, w11) FMA4(b, xv.z, w12) FMA4(b, xv.w, w13)
    }
}

__device__ __forceinline__ void pass1_lds(const float* sm, int xb, int w0, int fg4, float a[4])
{
    #pragma unroll 2
    for (int i4 = 0; i4 < 32; i4 += 4) {
        float4 xv  = *(const float4*)&sm[xb + i4];
        float4 w00 = *(const float4*)&sm[w0 + (i4+0)*32 + fg4];
        float4 w01 = *(const float4*)&sm[w0 + (i4+1)*32 + fg4];
        float4 w02 = *(const float4*)&sm[w0 + (i4+2)*32 + fg4];
        float4 w03 = *(const float4*)&sm[w0 + (i4+3)*32 + fg4];
        FMA4(a, xv.x, w00) FMA4(a, xv.y, w01) FMA4(a, xv.z, w02) FMA4(a, xv.w, w03)
    }
}

// ---------------- tab: proj (writes h). fallback additionally builds G table (stride 288) ----------------
#define TW 3072
__global__ __launch_bounds__(256, 2) void k_tab(
    const float* __restrict__ x, const float* __restrict__ proj_w, const float* __restrict__ proj_b,
    const float* __restrict__ e2w, const float* __restrict__ e2b,
    const int* __restrict__ flag,
    float* __restrict__ h, float* __restrict__ A, int N)
{
    __shared__ float sm[TW + 4*288];
    int tid = threadIdx.x;
    int lane = tid & 63;
    int w = tid >> 6;
    int fg = lane & 7, fg4 = fg*4;
    int nw = lane >> 3;
    int n = (blockIdx.x * 4 + w) * 8 + nw;
    bool valid = (n < N);
    int nc = valid ? n : (N - 1);
    int xb = TW + w*288 + nw*36;

    // proj: h row for this node
    {
        float4 xv = *(const float4*)&x[nc*4];
        float r_[4];
        #pragma unroll
        for (int j = 0; j < 4; ++j) {
            int o = fg4 + j;
            float a = proj_b[o];
            a = fmaf(xv.x, proj_w[0*32 + o], a);
            a = fmaf(xv.y, proj_w[1*32 + o], a);
            a = fmaf(xv.z, proj_w[2*32 + o], a);
            a = fmaf(xv.w, proj_w[3*32 + o], a);
            r_[j] = fmaxf(a, 0.f);
        }
        if (valid) *(float4*)&h[n*32 + fg4] = make_float4(r_[0], r_[1], r_[2], r_[3]);
        *(float4*)&sm[xb + fg4] = make_float4(r_[0], r_[1], r_[2], r_[3]);
    }

    if (!flag[0]) {
        // fallback: build G table for edge gather
        #pragma unroll 1
        for (int cg = 0; cg < 3; ++cg) {
            __syncthreads();
            float4* s4 = (float4*)sm;
            for (int i = tid; i < 768; i += 256) {
                int c = cg*3 + (i >> 8);
                const float4* src = (c < 8) ? (const float4*)(e2w + (size_t)c*1024)
                                            : (const float4*)e2b;
                s4[i] = src[i & 255];
            }
            __syncthreads();
            #pragma unroll 1
            for (int cc = 0; cc < 3; ++cc) {
                float acc[4] = {0.f, 0.f, 0.f, 0.f};
                pass1_lds(sm, xb, cc*1024, fg4, acc);
                if (valid)
                    *(float4*)&A[(size_t)n*288 + (cg*3+cc)*32 + fg4] =
                        make_float4(acc[0], acc[1], acc[2], acc[3]);
            }
        }
    }
}

// ---------------- fused iteration: u-vector gather from hIN -> agg GEMVs -> GRU -> hOUT ----------------
// Fast path: agg = u+@MP + u-@MM + u0@e2b (exact for e1b==0); no T table at all.
// LDS floats: ROOT[0,1024) WH[1024,4096) WI[4096,7168) MW[7168,10240) X[10240,+1152)
#define XGR 10240
__global__ __launch_bounds__(256, 2) void k_gru(
    const float* __restrict__ hIN, float* __restrict__ hOUT,
    const int* __restrict__ rowptr, const int* __restrict__ esrc, const float* __restrict__ eattr,
    const float* __restrict__ TIN, const int* __restrict__ flag,
    const float* __restrict__ root_w, const float* __restrict__ conv_b,
    const float* __restrict__ WI, const float* __restrict__ WH, const float* __restrict__ BS,
    const float* __restrict__ MP, const float* __restrict__ MM,
    const float* __restrict__ e2b, const float* __restrict__ e2w,
    const float* __restrict__ e1w, const float* __restrict__ e1b,
    float* __restrict__ TOUT, int N, int computeT)
{
    __shared__ float sm[XGR + 1152];
    int tid = threadIdx.x;
    int fast = flag[0];
    {
        float4* s4 = (float4*)sm;
        const float4* r4  = (const float4*)root_w;
        const float4* wh4 = (const float4*)WH;
        const float4* wi4 = (const float4*)WI;
        for (int i = tid; i < 256; i += 256) s4[i] = r4[i];
        for (int i = tid; i < 768; i += 256) s4[256  + i] = wh4[i];
        for (int i = tid; i < 768; i += 256) s4[1024 + i] = wi4[i];
        if (fast) {
            // MW = MP | MM | e2b  (needed every iteration for the u-vector GEMVs)
            for (int i = tid; i < 768; i += 256) {
                const float4* src = (i < 256) ? (const float4*)MP
                                  : (i < 512) ? (const float4*)MM
                                              : (const float4*)e2b;
                s4[1792 + i] = src[i & 255];
            }
        }
    }
    __syncthreads();

    int lane = tid & 63;
    int w = tid >> 6;
    int fg = lane & 7, fg4 = fg*4;
    int nw = lane >> 3;
    int n = (blockIdx.x * 4 + w) * 8 + nw;
    bool valid = (n < N);
    int nc = valid ? n : (N - 1);
    int xb = XGR + w*288 + nw*36;

    float4 hv4 = *(const float4*)&hIN[nc*32 + fg4];
    float hold[4] = {hv4.x, hv4.y, hv4.z, hv4.w};

    float av[4] = {0.f, 0.f, 0.f, 0.f};
    if (fast) {
        // ---- u-vector gather: 1 float4 load per edge per lane (half of T-row gather) ----
        float up[4] = {0.f,0.f,0.f,0.f};
        float um[4] = {0.f,0.f,0.f,0.f};
        float u0[4] = {0.f,0.f,0.f,0.f};
        int beg = rowptr[nc];
        int end = rowptr[nc + 1];
        int j = beg;
        for (; j + 3 < end; j += 4) {
            int s0 = esrc[j],     s1 = esrc[j + 1];
            int s2 = esrc[j + 2], s3 = esrc[j + 3];
            float a0 = eattr[j],     a1 = eattr[j + 1];
            float a2 = eattr[j + 2], a3 = eattr[j + 3];
            float4 g0 = *(const float4*)&hIN[(size_t)s0*32 + fg4];
            float4 g1 = *(const float4*)&hIN[(size_t)s1*32 + fg4];
            float4 g2 = *(const float4*)&hIN[(size_t)s2*32 + fg4];
            float4 g3 = *(const float4*)&hIN[(size_t)s3*32 + fg4];
            float p0 = fmaxf(a0, 0.f), m0 = fminf(a0, 0.f);
            float p1 = fmaxf(a1, 0.f), m1 = fminf(a1, 0.f);
            float p2 = fmaxf(a2, 0.f), m2 = fminf(a2, 0.f);
            float p3 = fmaxf(a3, 0.f), m3 = fminf(a3, 0.f);
            FMA4(up, p0, g0) FMA4(up, p1, g1) FMA4(up, p2, g2) FMA4(up, p3, g3)
            FMA4(um, m0, g0) FMA4(um, m1, g1) FMA4(um, m2, g2) FMA4(um, m3, g3)
            u0[0] += g0.x + g1.x + g2.x + g3.x;
            u0[1] += g0.y + g1.y + g2.y + g3.y;
            u0[2] += g0.z + g1.z + g2.z + g3.z;
            u0[3] += g0.w + g1.w + g2.w + g3.w;
        }
        for (; j < end; ++j) {
            int s0 = esrc[j];
            float a0 = eattr[j];
            float4 g0 = *(const float4*)&hIN[(size_t)s0*32 + fg4];
            float p0 = fmaxf(a0, 0.f), m0 = fminf(a0, 0.f);
            FMA4(up, p0, g0)
            FMA4(um, m0, g0)
            u0[0] += g0.x; u0[1] += g0.y; u0[2] += g0.z; u0[3] += g0.w;
        }
        // ---- agg = up@MP + um@MM + u0@e2b via sequential wave-local row publishes ----
        *(float4*)&sm[xb + fg4] = make_float4(up[0], up[1], up[2], up[3]);
        pass1_lds(sm, xb, 7168, fg4, av);
        *(float4*)&sm[xb + fg4] = make_float4(um[0], um[1], um[2], um[3]);
        pass1_lds(sm, xb, 8192, fg4, av);
        *(float4*)&sm[xb + fg4] = make_float4(u0[0], u0[1], u0[2], u0[3]);
        pass1_lds(sm, xb, 9216, fg4, av);
    } else {
        // fallback: 9-row G gather (e1b != 0), exact
        int beg = rowptr[nc];
        int end = rowptr[nc + 1];
        for (int j = beg; j < end; ++j) {
            int src = esrc[j];
            float a = eattr[j];
            const float* Gp = TIN + (size_t)src * 288;
            float4 b = *(const float4*)&Gp[256 + fg4];
            float m0 = b.x, m1 = b.y, m2 = b.z, m3 = b.w;
            #pragma unroll
            for (int k = 0; k < 8; ++k) {
                float t = fmaxf(fmaf(a, e1w[k], e1b[k]), 0.f);
                float4 g = *(const float4*)&Gp[k*32 + fg4];
                m0 = fmaf(t, g.x, m0); m1 = fmaf(t, g.y, m1);
                m2 = fmaf(t, g.z, m2); m3 = fmaf(t, g.w, m3);
            }
            av[0] += m0; av[1] += m1; av[2] += m2; av[3] += m3;
        }
    }

    // ---- publish h row; out_pre = agg + conv_b + h@root_w ; gh2 = bh2 + h@WH2 ----
    *(float4*)&sm[xb + fg4] = hv4;
    float outv[4], gh2[4];
    {
        float4 cb4 = *(const float4*)&conv_b[fg4];
        outv[0]=av[0]+cb4.x; outv[1]=av[1]+cb4.y; outv[2]=av[2]+cb4.z; outv[3]=av[3]+cb4.w;
        float4 b3 = *(const float4*)&BS[96 + fg4];
        gh2[0]=b3.x; gh2[1]=b3.y; gh2[2]=b3.z; gh2[3]=b3.w;
    }
    pass2_lds(sm, xb, 0, 1024 + 2048, fg4, outv, gh2);

    float gh0[4] = {0.f,0.f,0.f,0.f};
    float gh1[4] = {0.f,0.f,0.f,0.f};
    pass2_lds(sm, xb, 1024, 2048, fg4, gh0, gh1);

    float outr[4];
    #pragma unroll
    for (int j = 0; j < 4; ++j) outr[j] = fmaxf(outv[j], 0.f);

    *(float4*)&sm[xb + fg4] = make_float4(outr[0], outr[1], outr[2], outr[3]);

    float gi0[4], gi1[4], gi2[4];
    {
        float4 b0 = *(const float4*)&BS[fg4];
        float4 b1 = *(const float4*)&BS[32 + fg4];
        float4 b2 = *(const float4*)&BS[64 + fg4];
        gi0[0]=b0.x; gi0[1]=b0.y; gi0[2]=b0.z; gi0[3]=b0.w;
        gi1[0]=b1.x; gi1[1]=b1.y; gi1[2]=b1.z; gi1[3]=b1.w;
        gi2[0]=b2.x; gi2[1]=b2.y; gi2[2]=b2.z; gi2[3]=b2.w;
    }
    pass2_lds(sm, xb, 4096, 5120, fg4, gi0, gi1);
    pass1_lds(sm, xb, 6144, fg4, gi2);

    float hnew[4];
    #pragma unroll
    for (int j = 0; j < 4; ++j) {
        float r = sigmoidf_(gi0[j] + gh0[j]);
        float z = sigmoidf_(gi1[j] + gh1[j]);
        float nn = tanhf(gi2[j] + r * gh2[j]);
        hnew[j] = (1.f - z) * nn + z * hold[j];
    }
    if (valid) *(float4*)&hOUT[n*32 + fg4] = make_float4(hnew[0], hnew[1], hnew[2], hnew[3]);

    // ---- fallback only: recompute G table for next iteration ----
    if (!fast && computeT) {
        *(float4*)&sm[xb + fg4] = make_float4(hnew[0], hnew[1], hnew[2], hnew[3]);
        #pragma unroll 1
        for (int cg = 0; cg < 3; ++cg) {
            __syncthreads();
            float4* s4 = (float4*)sm;
            for (int i = tid; i < 768; i += 256) {
                int c = cg*3 + (i >> 8);
                const float4* src = (c < 8) ? (const float4*)(e2w + (size_t)c*1024)
                                            : (const float4*)e2b;
                s4[1792 + i] = src[i & 255];
            }
            __syncthreads();
            #pragma unroll 1
            for (int cc = 0; cc < 3; ++cc) {
                float acc[4] = {0.f, 0.f, 0.f, 0.f};
                pass1_lds(sm, xb, 7168 + cc*1024, fg4, acc);
                if (valid)
                    *(float4*)&TOUT[(size_t)n*288 + (cg*3+cc)*32 + fg4] =
                        make_float4(acc[0], acc[1], acc[2], acc[3]);
            }
        }
    }
}

// ---------------- readout pass1: e[n] = h[n]·q, segment max ----------------
__global__ __launch_bounds__(256) void k_pass1(
    const float* __restrict__ h, const int* __restrict__ batch,
    const float* __restrict__ qvec, float* __restrict__ ebuf,
    unsigned int* __restrict__ segmax, int N)
{
    int b = blockIdx.x / CHUNKS;
    int c = blockIdx.x % CHUNKS;
    int lo = 0, hi = N;
    while (lo < hi) { int mid = (lo + hi) >> 1; if (batch[mid] < b) lo = mid + 1; else hi = mid; }
    int s = lo;
    lo = 0; hi = N;
    while (lo < hi) { int mid = (lo + hi) >> 1; if (batch[mid] < b + 1) lo = mid + 1; else hi = mid; }
    int e = lo;
    int len = e - s;
    int per = (len + CHUNKS - 1) / CHUNKS;
    int n0 = s + c * per;
    int n1 = min(n0 + per, e);

    int tid = threadIdx.x;
    int ln = tid >> 5, o = tid & 31;
    float qv = qvec[o];
    float mloc = -INFINITY;
    for (int nn = n0 + ln; nn < n1; nn += 8) {
        float v = h[nn * H + o] * qv;
        #pragma unroll
        for (int m = 16; m >= 1; m >>= 1) v += __shfl_xor(v, m);
        if (o == 0) ebuf[nn] = v;
        mloc = fmaxf(mloc, v);
    }
    __shared__ float red[256];
    red[tid] = mloc;
    __syncthreads();
    for (int st = 128; st >= 1; st >>= 1) {
        if (tid < st) red[tid] = fmaxf(red[tid], red[tid + st]);
        __syncthreads();
    }
    if (tid == 0 && n0 < n1) atomicMax(&segmax[b], fenc(red[0]));
}

// ---------------- readout pass2: a = exp(e - emax); vsum += a*h; ssum += a ----------------
__global__ __launch_bounds__(256) void k_pass2(
    const float* __restrict__ h, const int* __restrict__ batch,
    const float* __restrict__ ebuf, const unsigned int* __restrict__ segmax,
    float* __restrict__ ssum, float* __restrict__ vsum, int N)
{
    int b = blockIdx.x / CHUNKS;
    int c = blockIdx.x % CHUNKS;
    int lo = 0, hi = N;
    while (lo < hi) { int mid = (lo + hi) >> 1; if (batch[mid] < b) lo = mid + 1; else hi = mid; }
    int s = lo;
    lo = 0; hi = N;
    while (lo < hi) { int mid = (lo + hi) >> 1; if (batch[mid] < b + 1) lo = mid + 1; else hi = mid; }
    int e = lo;
    int len = e - s;
    int per = (len + CHUNKS - 1) / CHUNKS;
    int n0 = s + c * per;
    int n1 = min(n0 + per, e);

    int tid = threadIdx.x;
    int ln = tid >> 5, o = tid & 31;
    float emax = fdec(segmax[b]);
    float vacc = 0.f, sacc = 0.f;
    for (int nn = n0 + ln; nn < n1; nn += 8) {
        float a = expf(ebuf[nn] - emax);
        vacc += a * h[nn * H + o];
        if (o == 0) sacc += a;
    }
    __shared__ float vsh[8][H];
    __shared__ float ssh[8];
    vsh[ln][o] = vacc;
    if (o == 0) ssh[ln] = sacc;
    __syncthreads();
    if (tid < H) {
        float v = 0.f;
        #pragma unroll
        for (int g = 0; g < 8; ++g) v += vsh[g][tid];
        atomicAdd(&vsum[b * H + tid], v);
    } else if (tid == H) {
        float stot = 0.f;
        #pragma unroll
        for (int g = 0; g < 8; ++g) stot += ssh[g];
        atomicAdd(&ssum[b], stot);
    }
}

// ---------------- final MLP on (16, 64) ----------------
__global__ __launch_bounds__(512) void k_mlp(
    const float* __restrict__ qvec, const float* __restrict__ ssum, const float* __restrict__ vsum,
    const float* __restrict__ f1w, const float* __restrict__ f1b,
    const float* __restrict__ f2w, const float* __restrict__ f2b,
    const float* __restrict__ f3w, const float* __restrict__ f3b,
    float* __restrict__ out)
{
    __shared__ float qsm[BSEG][2 * H];
    __shared__ float o1[BSEG][H];
    __shared__ float o2[BSEG][H];
    int tid = threadIdx.x;
    int b = tid >> 5, j = tid & 31;
    float st = ssum[b];
    qsm[b][j] = qvec[j];
    qsm[b][H + j] = (st > 0.f) ? vsum[b * H + j] / st : 0.f;
    __syncthreads();
    float acc = f1b[j];
    for (int i = 0; i < 2 * H; ++i) acc += qsm[b][i] * f1w[i * H + j];
    o1[b][j] = fmaxf(acc, 0.f);
    __syncthreads();
    acc = f2b[j];
    for (int i = 0; i < H; ++i) acc += o1[b][i] * f2w[i * H + j];
    o2[b][j] = fmaxf(acc, 0.f);
    __syncthreads();
    float v = o2[b][j] * f3w[j];
    #pragma unroll
    for (int m = 16; m >= 1; m >>= 1) v += __shfl_xor(v, m);
    if (j == 0) out[b] = v + f3b[0];
}

extern "C" void kernel_launch(void* const* d_in, const int* in_sizes, int n_in,
                              void* d_out, int out_size, void* d_ws, size_t ws_size,
                              hipStream_t stream)
{
    const float* x      = (const float*)d_in[0];
    const int*   ei     = (const int*)d_in[1];
    const float* ea     = (const float*)d_in[2];
    const int*   batch  = (const int*)d_in[3];
    const float* proj_w = (const float*)d_in[4];
    const float* proj_b = (const float*)d_in[5];
    const float* e1w    = (const float*)d_in[6];
    const float* e1b    = (const float*)d_in[7];
    const float* e2w    = (const float*)d_in[8];
    const float* e2b    = (const float*)d_in[9];
    const float* root_w = (const float*)d_in[10];
    const float* conv_b = (const float*)d_in[11];
    const float* gru_wi = (const float*)d_in[12];
    const float* gru_wh = (const float*)d_in[13];
    const float* gru_bi = (const float*)d_in[14];
    const float* gru_bh = (const float*)d_in[15];
    const float* lstm_bi = (const float*)d_in[18];
    const float* lstm_bh = (const float*)d_in[19];
    const float* f1w    = (const float*)d_in[20];
    const float* f1b    = (const float*)d_in[21];
    const float* f2w    = (const float*)d_in[22];
    const float* f2b    = (const float*)d_in[23];
    const float* f3w    = (const float*)d_in[24];
    const float* f3b    = (const float*)d_in[25];

    const int N = in_sizes[0] / 4;
    const int E = in_sizes[2];

    float* ws   = (float*)d_ws;
    float* hA   = ws;                        // N*32 (ping)
    float* hB   = hA + (size_t)N * H;        // N*32 (pong)
    float* A    = hB + (size_t)N * H;        // N*288 (fallback G ping)
    float* Bb   = A + (size_t)N * 288;       // N*288 (fallback G pong)
    float* ebuf = Bb + (size_t)N * 288;      // N
    float* qvec = ebuf + N;                  // 32
    unsigned int* segmax = (unsigned int*)(qvec + H);  // 16
    float* ssum = (float*)(segmax + BSEG);   // 16
    float* vsum = ssum + BSEG;               // 512
    float* WI   = vsum + BSEG * H;           // 3072
    float* WH   = WI + 3072;                 // 3072
    float* BS   = WH + 3072;                 // 128
    float* MP   = BS + 128;                  // 1024
    float* MM   = MP + 1024;                 // 1024
    int*   flag = (int*)(MM + 1024);         // 1
    int*   cnt    = flag + 1;                // N
    int*   rowptr = cnt + N;                 // N+1
    int*   cursor = rowptr + N + 1;          // N
    int*   esrc   = cursor + N;              // E
    float* eattr  = (float*)(esrc + E);      // E

    const int nwaves = (N + 7) / 8;          // 8 nodes per wave
    const int nb4 = (nwaves + 3) / 4;        // 4 waves per block
    const int cblocks = (E + 255) / 256;

    k_prep<<<1, 512, 0, stream>>>(gru_wi, gru_wh, gru_bi, gru_bh, lstm_bi, lstm_bh,
                                  e1w, e1b, e2w,
                                  WI, WH, BS, MP, MM, flag, qvec, segmax, ssum, vsum, cnt, N);
    k_count<<<cblocks, 256, 0, stream>>>(ei, cnt, E);
    k_scan<<<1, 1024, 0, stream>>>(cnt, rowptr, cursor, N);
    k_scatter<<<cblocks, 256, 0, stream>>>(ei, ea, cursor, esrc, eattr, E);
    k_tab<<<nb4, 256, 0, stream>>>(x, proj_w, proj_b, e2w, e2b, flag, hA, A, N);

    k_gru<<<nb4, 256, 0, stream>>>(hA, hB, rowptr, esrc, eattr, A, flag, root_w, conv_b,
                                   WI, WH, BS, MP, MM, e2b, e2w, e1w, e1b, Bb, N, 1);
    k_gru<<<nb4, 256, 0, stream>>>(hB, hA, rowptr, esrc, eattr, Bb, flag, root_w, conv_b,
                                   WI, WH, BS, MP, MM, e2b, e2w, e1w, e1b, A, N, 1);
    k_gru<<<nb4, 256, 0, stream>>>(hA, hB, rowptr, esrc, eattr, A, flag, root_w, conv_b,
                                   WI, WH, BS, MP, MM, e2b, e2w, e1w, e1b, Bb, N, 0);

    k_pass1<<<BSEG * CHUNKS, 256, 0, stream>>>(hB, batch, qvec, ebuf, segmax, N);
    k_pass2<<<BSEG * CHUNKS, 256, 0, stream>>>(hB, batch, ebuf, segmax, ssum, vsum, N);
    k_mlp<<<1, 512, 0, stream>>>(qvec, ssum, vsum, f1w, f1b, f2w, f2b, f3w, f3b, (float*)d_out);
}